// Round 1
// baseline (1410.336 us; speedup 1.0000x reference)
//
#include <hip/hip_runtime.h>
#include <hip/hip_bf16.h>

// ---------------------------------------------------------------------------
// 2-layer GAT (PyG GATConv semantics), all-f32 pipeline.
// Layer1: h1 = x@W1 [N,256]; attention softmax over incoming edges (4 heads);
//         agg + b1 -> ELU.  Layer2: same with W2, then head-mean + b2.
// Final:  out2 @ Wout + bout -> d_out [N,16].
// Softmax max-subtraction skipped (cancels exactly in alpha; exp args bounded).
// ---------------------------------------------------------------------------

#define HEADS 4
#define CDIM 64
#define HC 256  // HEADS*CDIM

// ---------------- f32 tiled GEMM: C[M,N] = A[M,K] @ B[K,N] -----------------
// 64x64 tile, 256 threads, 4x4 microtile, K-tile 16. N,K multiples of 16/64.
#define TS 64
#define KT 16
__global__ __launch_bounds__(256) void gemm_f32(
    const float* __restrict__ A, const float* __restrict__ B,
    float* __restrict__ C, int M, int N, int K) {
  __shared__ float As[KT][TS + 1];
  __shared__ float Bs[KT][TS + 1];
  const int tx = threadIdx.x & 15;       // 0..15 (cols)
  const int ty = threadIdx.x >> 4;       // 0..15 (rows)
  const int row0 = blockIdx.x * TS;
  const int col0 = blockIdx.y * TS;
  float acc[4][4] = {};
  for (int k0 = 0; k0 < K; k0 += KT) {
    // A tile: 64 rows x 16 k
    for (int i = threadIdx.x; i < TS * KT; i += 256) {
      int r = i >> 4, c = i & 15;
      int gr = row0 + r;
      As[c][r] = (gr < M) ? A[(long long)gr * K + k0 + c] : 0.f;
    }
    // B tile: 16 k x 64 cols
    for (int i = threadIdx.x; i < KT * TS; i += 256) {
      int r = i >> 6, c = i & 63;
      Bs[r][c] = B[(long long)(k0 + r) * N + col0 + c];
    }
    __syncthreads();
#pragma unroll
    for (int kk = 0; kk < KT; ++kk) {
      float a[4], b[4];
#pragma unroll
      for (int i = 0; i < 4; i++) a[i] = As[kk][ty * 4 + i];
#pragma unroll
      for (int j = 0; j < 4; j++) b[j] = Bs[kk][tx * 4 + j];
#pragma unroll
      for (int i = 0; i < 4; i++)
#pragma unroll
        for (int j = 0; j < 4; j++) acc[i][j] += a[i] * b[j];
    }
    __syncthreads();
  }
#pragma unroll
  for (int i = 0; i < 4; i++) {
    int gr = row0 + ty * 4 + i;
    if (gr >= M) continue;
#pragma unroll
    for (int j = 0; j < 4; j++)
      C[(long long)gr * N + col0 + tx * 4 + j] = acc[i][j];
  }
}

// -------- per-node attention scores: a_s[n,h] = <h[n,h,:], att_s[h,:]> -----
// block = 1 node (256 thr), wave = 1 head (64 lanes), shuffle reduce.
__global__ __launch_bounds__(256) void att_score_kernel(
    const float* __restrict__ h, const float* __restrict__ att_s,
    const float* __restrict__ att_d, float* __restrict__ a_s,
    float* __restrict__ a_d) {
  const int n = blockIdx.x;
  const int head = threadIdx.x >> 6;
  const int lane = threadIdx.x & 63;
  const float v = h[n * HC + head * CDIM + lane];
  float s = v * att_s[head * CDIM + lane];
  float d = v * att_d[head * CDIM + lane];
#pragma unroll
  for (int off = 32; off > 0; off >>= 1) {
    s += __shfl_down(s, off);
    d += __shfl_down(d, off);
  }
  if (lane == 0) {
    a_s[n * HEADS + head] = s;
    a_d[n * HEADS + head] = d;
  }
}

// -------- edge pass 1: ex = exp(leaky_relu(a_s[src]+a_d[dst])); denom += ---
__global__ __launch_bounds__(256) void edge_exp_kernel(
    const int* __restrict__ src, const int* __restrict__ dst,
    const float* __restrict__ a_s, const float* __restrict__ a_d,
    float* __restrict__ ex, float* __restrict__ denom, int E_raw, int Etot4) {
  const int i = blockIdx.x * 256 + threadIdx.x;
  if (i >= Etot4) return;
  const int e = i >> 2, hh = i & 3;
  const int s = (e < E_raw) ? src[e] : (e - E_raw);
  const int d = (e < E_raw) ? dst[e] : (e - E_raw);
  float a = a_s[s * HEADS + hh] + a_d[d * HEADS + hh];
  a = (a > 0.f) ? a : 0.2f * a;  // leaky_relu, PyG default slope
  const float x = __expf(a);
  ex[i] = x;
  atomicAdd(&denom[d * HEADS + hh], x);
}

// -------- edge pass 2: ex -> alpha = ex / denom[dst] -----------------------
__global__ __launch_bounds__(256) void edge_alpha_kernel(
    const int* __restrict__ dst, const float* __restrict__ denom,
    float* __restrict__ ex, int E_raw, int Etot4) {
  const int i = blockIdx.x * 256 + threadIdx.x;
  if (i >= Etot4) return;
  const int e = i >> 2, hh = i & 3;
  const int d = (e < E_raw) ? dst[e] : (e - E_raw);
  ex[i] = ex[i] / denom[d * HEADS + hh];
}

// -------- edge pass 3: agg[dst,:] += alpha[e,h] * h[src,:] -----------------
// one block per edge; 256 threads = 256 components (4 heads x 64).
__global__ __launch_bounds__(256) void edge_message_kernel(
    const int* __restrict__ src, const int* __restrict__ dst,
    const float* __restrict__ h, const float* __restrict__ alpha,
    float* __restrict__ agg, int E_raw) {
  const int e = blockIdx.x;
  const int c = threadIdx.x;
  const int s = (e < E_raw) ? src[e] : (e - E_raw);
  const int d = (e < E_raw) ? dst[e] : (e - E_raw);
  const float al = alpha[e * HEADS + (c >> 6)];
  atomicAdd(&agg[(long long)d * HC + c], al * h[(long long)s * HC + c]);
}

// -------- layer-1 epilogue: in-place  a = ELU(a + b1) ----------------------
__global__ __launch_bounds__(256) void elu_bias_kernel(
    float* __restrict__ a, const float* __restrict__ b, int total) {
  const int i = blockIdx.x * 256 + threadIdx.x;
  if (i >= total) return;
  float v = a[i] + b[i & (HC - 1)];
  a[i] = (v > 0.f) ? v : (__expf(v) - 1.f);
}

// -------- layer-2 epilogue: out2[n,c] = mean_h agg[n,h,c] + b2[c] ----------
__global__ __launch_bounds__(256) void mean_bias_kernel(
    const float* __restrict__ agg, const float* __restrict__ b,
    float* __restrict__ out, int total) {
  const int i = blockIdx.x * 256 + threadIdx.x;
  if (i >= total) return;
  const int n = i >> 6, c = i & 63;
  const float v = 0.25f * (agg[n * HC + c] + agg[n * HC + CDIM + c] +
                           agg[n * HC + 2 * CDIM + c] + agg[n * HC + 3 * CDIM + c]);
  out[i] = v + b[c];
}

// -------- final: d_out[n,j] = out2[n,:] @ Wout[:,j] + bout[j] --------------
__global__ __launch_bounds__(256) void final_gemm_kernel(
    const float* __restrict__ X, const float* __restrict__ W,
    const float* __restrict__ b, float* __restrict__ out, int total) {
  const int i = blockIdx.x * 256 + threadIdx.x;
  if (i >= total) return;
  const int n = i >> 4, j = i & 15;
  float s = b[j];
#pragma unroll
  for (int k = 0; k < CDIM; ++k) s += X[n * CDIM + k] * W[k * 16 + j];
  out[i] = s;
}

extern "C" void kernel_launch(void* const* d_in, const int* in_sizes, int n_in,
                              void* d_out, int out_size, void* d_ws, size_t ws_size,
                              hipStream_t stream) {
  const float* x        = (const float*)d_in[0];
  const int*   eidx     = (const int*)d_in[1];
  const float* W1       = (const float*)d_in[2];
  const float* att_s1   = (const float*)d_in[3];
  const float* att_d1   = (const float*)d_in[4];
  const float* b1       = (const float*)d_in[5];
  const float* W2       = (const float*)d_in[6];
  const float* att_s2   = (const float*)d_in[7];
  const float* att_d2   = (const float*)d_in[8];
  const float* b2       = (const float*)d_in[9];
  const float* Wout     = (const float*)d_in[10];
  const float* bout     = (const float*)d_in[11];
  float* out            = (float*)d_out;

  const int N     = in_sizes[0] / 128;      // 20000 nodes
  const int E_raw = in_sizes[1] / 2;        // 640000 edges
  const int Etot  = E_raw + N;              // + self loops
  const int Etot4 = Etot * HEADS;
  const int* src = eidx;
  const int* dst = eidx + E_raw;

  // ---- workspace layout (floats) ----
  float* ws = (float*)d_ws;
  float* buf_h     = ws;                       // [N,256] h1 then h2
  float* buf_agg   = buf_h + (size_t)N * HC;   // [N,256] agg1/ELU-out/agg2
  float* buf_ex    = buf_agg + (size_t)N * HC; // [Etot,4] ex -> alpha
  float* buf_as    = buf_ex + (size_t)Etot4;   // [N,4]
  float* buf_ad    = buf_as + (size_t)N * HEADS;
  float* buf_denom = buf_ad + (size_t)N * HEADS;
  float* buf_out2  = buf_denom + (size_t)N * HEADS;  // [N,64]

  const dim3 blk(256);
  const dim3 g_gemm((N + TS - 1) / TS, HC / TS);
  const int g_edge4 = (Etot4 + 255) / 256;
  const int g_nhc   = (N * HC + 255) / 256;

  // ================= Layer 1 =================
  gemm_f32<<<g_gemm, blk, 0, stream>>>(x, W1, buf_h, N, HC, 128);
  att_score_kernel<<<N, blk, 0, stream>>>(buf_h, att_s1, att_d1, buf_as, buf_ad);
  hipMemsetAsync(buf_denom, 0, (size_t)N * HEADS * sizeof(float), stream);
  edge_exp_kernel<<<g_edge4, blk, 0, stream>>>(src, dst, buf_as, buf_ad,
                                               buf_ex, buf_denom, E_raw, Etot4);
  edge_alpha_kernel<<<g_edge4, blk, 0, stream>>>(dst, buf_denom, buf_ex, E_raw, Etot4);
  hipMemsetAsync(buf_agg, 0, (size_t)N * HC * sizeof(float), stream);
  edge_message_kernel<<<Etot, blk, 0, stream>>>(src, dst, buf_h, buf_ex, buf_agg, E_raw);
  elu_bias_kernel<<<g_nhc, blk, 0, stream>>>(buf_agg, b1, N * HC);

  // ================= Layer 2 =================
  gemm_f32<<<g_gemm, blk, 0, stream>>>(buf_agg, W2, buf_h, N, HC, HC);
  att_score_kernel<<<N, blk, 0, stream>>>(buf_h, att_s2, att_d2, buf_as, buf_ad);
  hipMemsetAsync(buf_denom, 0, (size_t)N * HEADS * sizeof(float), stream);
  edge_exp_kernel<<<g_edge4, blk, 0, stream>>>(src, dst, buf_as, buf_ad,
                                               buf_ex, buf_denom, E_raw, Etot4);
  edge_alpha_kernel<<<g_edge4, blk, 0, stream>>>(dst, buf_denom, buf_ex, E_raw, Etot4);
  hipMemsetAsync(buf_agg, 0, (size_t)N * HC * sizeof(float), stream);  // gemm2 already consumed it
  edge_message_kernel<<<Etot, blk, 0, stream>>>(src, dst, buf_h, buf_ex, buf_agg, E_raw);
  mean_bias_kernel<<<(N * CDIM + 255) / 256, blk, 0, stream>>>(buf_agg, b2, buf_out2, N * CDIM);

  // ================= Output head =================
  final_gemm_kernel<<<(N * 16 + 255) / 256, blk, 0, stream>>>(buf_out2, Wout, bout,
                                                              out, N * 16);
}

// Round 2
// 579.444 us; speedup vs baseline: 2.4339x; 2.4339x over previous
//
#include <hip/hip_runtime.h>
#include <hip/hip_bf16.h>

// ---------------------------------------------------------------------------
// 2-layer GAT (PyG GATConv semantics), all-f32 pipeline.
// Round 2: atomic scatter replaced by dst-CSR gather-reduce; softmax
// (exp/denominator) fused into the aggregation loop (max-sub cancels).
// CSR built once per call: degree histogram -> 2-level scan -> scatter.
// ---------------------------------------------------------------------------

#define HEADS 4
#define CDIM 64
#define HC 256  // HEADS*CDIM

// ---------------- f32 tiled GEMM: C[M,N] = A[M,K] @ B[K,N] -----------------
#define TS 64
#define KT 16
__global__ __launch_bounds__(256) void gemm_f32(
    const float* __restrict__ A, const float* __restrict__ B,
    float* __restrict__ C, int M, int N, int K) {
  __shared__ float As[KT][TS + 1];
  __shared__ float Bs[KT][TS + 1];
  const int tx = threadIdx.x & 15;
  const int ty = threadIdx.x >> 4;
  const int row0 = blockIdx.x * TS;
  const int col0 = blockIdx.y * TS;
  float acc[4][4] = {};
  for (int k0 = 0; k0 < K; k0 += KT) {
    for (int i = threadIdx.x; i < TS * KT; i += 256) {
      int r = i >> 4, c = i & 15;
      int gr = row0 + r;
      As[c][r] = (gr < M) ? A[(long long)gr * K + k0 + c] : 0.f;
    }
    for (int i = threadIdx.x; i < KT * TS; i += 256) {
      int r = i >> 6, c = i & 63;
      Bs[r][c] = B[(long long)(k0 + r) * N + col0 + c];
    }
    __syncthreads();
#pragma unroll
    for (int kk = 0; kk < KT; ++kk) {
      float a[4], b[4];
#pragma unroll
      for (int i = 0; i < 4; i++) a[i] = As[kk][ty * 4 + i];
#pragma unroll
      for (int j = 0; j < 4; j++) b[j] = Bs[kk][tx * 4 + j];
#pragma unroll
      for (int i = 0; i < 4; i++)
#pragma unroll
        for (int j = 0; j < 4; j++) acc[i][j] += a[i] * b[j];
    }
    __syncthreads();
  }
#pragma unroll
  for (int i = 0; i < 4; i++) {
    int gr = row0 + ty * 4 + i;
    if (gr >= M) continue;
#pragma unroll
    for (int j = 0; j < 4; j++)
      C[(long long)gr * N + col0 + tx * 4 + j] = acc[i][j];
  }
}

// -------- per-node attention scores: a_s[n,h] = <h[n,h,:], att_s[h,:]> -----
__global__ __launch_bounds__(256) void att_score_kernel(
    const float* __restrict__ h, const float* __restrict__ att_s,
    const float* __restrict__ att_d, float* __restrict__ a_s,
    float* __restrict__ a_d) {
  const int n = blockIdx.x;
  const int head = threadIdx.x >> 6;
  const int lane = threadIdx.x & 63;
  const float v = h[n * HC + head * CDIM + lane];
  float s = v * att_s[head * CDIM + lane];
  float d = v * att_d[head * CDIM + lane];
#pragma unroll
  for (int off = 32; off > 0; off >>= 1) {
    s += __shfl_down(s, off);
    d += __shfl_down(d, off);
  }
  if (lane == 0) {
    a_s[n * HEADS + head] = s;
    a_d[n * HEADS + head] = d;
  }
}

// ======================= CSR construction (per call) =======================
// 1) degree histogram over dst (incl. self-loops)
__global__ __launch_bounds__(256) void deg_count_kernel(
    const int* __restrict__ dst, int* __restrict__ deg, int E_raw, int Etot) {
  const int e = blockIdx.x * 256 + threadIdx.x;
  if (e >= Etot) return;
  const int d = (e < E_raw) ? dst[e] : (e - E_raw);
  atomicAdd(&deg[d], 1);
}

// 2a) per-256-block inclusive scan; write inclusive values + block sums
__global__ __launch_bounds__(256) void scan_block_kernel(
    const int* __restrict__ deg, int* __restrict__ incl,
    int* __restrict__ bsum, int N) {
  __shared__ int sm[256];
  const int t = threadIdx.x;
  const int i = blockIdx.x * 256 + t;
  int v = (i < N) ? deg[i] : 0;
  sm[t] = v;
  __syncthreads();
#pragma unroll
  for (int off = 1; off < 256; off <<= 1) {
    int x = (t >= off) ? sm[t - off] : 0;
    __syncthreads();
    sm[t] += x;
    __syncthreads();
  }
  if (i < N) incl[i] = sm[t];
  if (t == 255) bsum[blockIdx.x] = sm[255];
}

// 2b) single-block exclusive scan of block sums (nb <= 256)
__global__ __launch_bounds__(256) void scan_top_kernel(
    const int* __restrict__ bsum, int* __restrict__ boff, int nb) {
  __shared__ int sm[256];
  const int t = threadIdx.x;
  int v = (t < nb) ? bsum[t] : 0;
  sm[t] = v;
  __syncthreads();
#pragma unroll
  for (int off = 1; off < 256; off <<= 1) {
    int x = (t >= off) ? sm[t - off] : 0;
    __syncthreads();
    sm[t] += x;
    __syncthreads();
  }
  if (t < nb) boff[t] = sm[t] - v;  // exclusive
}

// 2c) finalize exclusive row_ptr + writable cursor copy
__global__ __launch_bounds__(256) void scan_final_kernel(
    const int* __restrict__ deg, const int* __restrict__ incl,
    const int* __restrict__ boff, int* __restrict__ row_ptr,
    int* __restrict__ cursor, int N, int Etot) {
  const int i = blockIdx.x * 256 + threadIdx.x;
  if (i == 0) row_ptr[N] = Etot;
  if (i >= N) return;
  const int v = boff[blockIdx.x] + incl[i] - deg[i];  // exclusive scan
  row_ptr[i] = v;
  cursor[i] = v;
}

// 3) scatter edges into CSR slots (src ids, grouped by dst)
__global__ __launch_bounds__(256) void csr_scatter_kernel(
    const int* __restrict__ src, const int* __restrict__ dst,
    int* __restrict__ cursor, int* __restrict__ csr_src, int E_raw, int Etot) {
  const int e = blockIdx.x * 256 + threadIdx.x;
  if (e >= Etot) return;
  const int s = (e < E_raw) ? src[e] : (e - E_raw);
  const int d = (e < E_raw) ? dst[e] : (e - E_raw);
  const int pos = atomicAdd(&cursor[d], 1);
  csr_src[pos] = s;
}

// ================= fused softmax + aggregation (gather) ====================
// one block per dst node; 256 threads = 4 heads x 64 channels.
// acc[c]  = sum_e exp(leaky(a_s[s]+a_d[n])) * h[s,c]
// den     = sum_e exp(...)          (identical across the 64 lanes of a head)
// mode 0: out[n,c]   = ELU(acc/den + b[c])        (layer 1, [N,256])
// mode 1: out[n,c64] = mean_h(acc/den) + b[c64]   (layer 2, [N,64])
__global__ __launch_bounds__(256) void gat_aggregate_kernel(
    const int* __restrict__ row_ptr, const int* __restrict__ csr_src,
    const float* __restrict__ h, const float* __restrict__ a_s,
    const float* __restrict__ a_d, const float* __restrict__ b,
    float* __restrict__ out, int mode) {
  const int n = blockIdx.x;
  const int c = threadIdx.x;
  const int hh = c >> 6;
  const float ad = a_d[n * HEADS + hh];
  const int beg = row_ptr[n];
  const int end = row_ptr[n + 1];
  float acc = 0.f, den = 0.f;
  for (int i = beg; i < end; ++i) {
    const int s = csr_src[i];
    float a = a_s[s * HEADS + hh] + ad;
    a = (a > 0.f) ? a : 0.2f * a;  // leaky_relu slope 0.2
    const float ex = __expf(a);
    den += ex;
    acc += ex * h[(long long)s * HC + c];
  }
  const float v = acc / den;
  if (mode == 0) {
    const float u = v + b[c];
    out[(long long)n * HC + c] = (u > 0.f) ? u : (__expf(u) - 1.f);
  } else {
    __shared__ float sm[HC];
    sm[c] = v;
    __syncthreads();
    if (c < CDIM) {
      out[(long long)n * CDIM + c] =
          0.25f * (sm[c] + sm[c + CDIM] + sm[c + 2 * CDIM] + sm[c + 3 * CDIM]) +
          b[c];
    }
  }
}

// -------- final: d_out[n,j] = out2[n,:] @ Wout[:,j] + bout[j] --------------
__global__ __launch_bounds__(256) void final_gemm_kernel(
    const float* __restrict__ X, const float* __restrict__ W,
    const float* __restrict__ b, float* __restrict__ out, int total) {
  const int i = blockIdx.x * 256 + threadIdx.x;
  if (i >= total) return;
  const int n = i >> 4, j = i & 15;
  float s = b[j];
#pragma unroll
  for (int k = 0; k < CDIM; ++k) s += X[n * CDIM + k] * W[k * 16 + j];
  out[i] = s;
}

extern "C" void kernel_launch(void* const* d_in, const int* in_sizes, int n_in,
                              void* d_out, int out_size, void* d_ws, size_t ws_size,
                              hipStream_t stream) {
  const float* x      = (const float*)d_in[0];
  const int*   eidx   = (const int*)d_in[1];
  const float* W1     = (const float*)d_in[2];
  const float* att_s1 = (const float*)d_in[3];
  const float* att_d1 = (const float*)d_in[4];
  const float* b1     = (const float*)d_in[5];
  const float* W2     = (const float*)d_in[6];
  const float* att_s2 = (const float*)d_in[7];
  const float* att_d2 = (const float*)d_in[8];
  const float* b2     = (const float*)d_in[9];
  const float* Wout   = (const float*)d_in[10];
  const float* bout   = (const float*)d_in[11];
  float* out          = (float*)d_out;

  const int N     = in_sizes[0] / 128;   // 20000
  const int E_raw = in_sizes[1] / 2;     // 640000
  const int Etot  = E_raw + N;           // + self loops
  const int* src = eidx;
  const int* dst = eidx + E_raw;
  const int NB = (N + 255) / 256;        // 79 scan blocks

  // ---- workspace layout ----
  float* ws = (float*)d_ws;
  float* buf_h    = ws;                        // [N,256]
  float* buf_agg  = buf_h + (size_t)N * HC;    // [N,256] layer-1 ELU output
  float* buf_as   = buf_agg + (size_t)N * HC;  // [N,4]
  float* buf_ad   = buf_as + (size_t)N * HEADS;
  float* buf_out2 = buf_ad + (size_t)N * HEADS;       // [N,64]
  int* deg     = (int*)(buf_out2 + (size_t)N * CDIM); // [N]
  int* incl    = deg + N;                             // [N]
  int* row_ptr = incl + N;                            // [N+1]
  int* cursor  = row_ptr + (N + 1);                   // [N]
  int* bsum    = cursor + N;                          // [NB]
  int* boff    = bsum + NB;                           // [NB]
  int* csr_src = boff + NB;                           // [Etot]

  const dim3 blk(256);
  const dim3 g_gemm((N + TS - 1) / TS, HC / TS);
  const int g_edge = (Etot + 255) / 256;

  // ================= CSR build (shared by both layers) =================
  hipMemsetAsync(deg, 0, (size_t)N * sizeof(int), stream);
  deg_count_kernel<<<g_edge, blk, 0, stream>>>(dst, deg, E_raw, Etot);
  scan_block_kernel<<<NB, blk, 0, stream>>>(deg, incl, bsum, N);
  scan_top_kernel<<<1, blk, 0, stream>>>(bsum, boff, NB);
  scan_final_kernel<<<NB, blk, 0, stream>>>(deg, incl, boff, row_ptr, cursor, N, Etot);
  csr_scatter_kernel<<<g_edge, blk, 0, stream>>>(src, dst, cursor, csr_src, E_raw, Etot);

  // ================= Layer 1 =================
  gemm_f32<<<g_gemm, blk, 0, stream>>>(x, W1, buf_h, N, HC, 128);
  att_score_kernel<<<N, blk, 0, stream>>>(buf_h, att_s1, att_d1, buf_as, buf_ad);
  gat_aggregate_kernel<<<N, blk, 0, stream>>>(row_ptr, csr_src, buf_h, buf_as,
                                              buf_ad, b1, buf_agg, 0);

  // ================= Layer 2 =================
  gemm_f32<<<g_gemm, blk, 0, stream>>>(buf_agg, W2, buf_h, N, HC, HC);
  att_score_kernel<<<N, blk, 0, stream>>>(buf_h, att_s2, att_d2, buf_as, buf_ad);
  gat_aggregate_kernel<<<N, blk, 0, stream>>>(row_ptr, csr_src, buf_h, buf_as,
                                              buf_ad, b2, buf_out2, 1);

  // ================= Output head =================
  final_gemm_kernel<<<(N * 16 + 255) / 256, blk, 0, stream>>>(buf_out2, Wout, bout,
                                                              out, N * 16);
}

// Round 3
// 461.507 us; speedup vs baseline: 3.0559x; 1.2555x over previous
//
#include <hip/hip_runtime.h>
#include <hip/hip_bf16.h>

// ---------------------------------------------------------------------------
// 2-layer GAT (PyG GATConv semantics), all-f32 pipeline.
// Round 3: gat_aggregate restructured for MLP — thread = (edge_slot, chan
// quad); 4 independent edges in flight per wave, float4 (16B) gathers,
// exp computed 64x/edge instead of 256x. LDS cross-slot reduction epilogue.
// ---------------------------------------------------------------------------

#define HEADS 4
#define CDIM 64
#define HC 256  // HEADS*CDIM

// ---------------- f32 tiled GEMM: C[M,N] = A[M,K] @ B[K,N] -----------------
#define TS 64
#define KT 16
__global__ __launch_bounds__(256) void gemm_f32(
    const float* __restrict__ A, const float* __restrict__ B,
    float* __restrict__ C, int M, int N, int K) {
  __shared__ float As[KT][TS + 1];
  __shared__ float Bs[KT][TS + 1];
  const int tx = threadIdx.x & 15;
  const int ty = threadIdx.x >> 4;
  const int row0 = blockIdx.x * TS;
  const int col0 = blockIdx.y * TS;
  float acc[4][4] = {};
  for (int k0 = 0; k0 < K; k0 += KT) {
    for (int i = threadIdx.x; i < TS * KT; i += 256) {
      int r = i >> 4, c = i & 15;
      int gr = row0 + r;
      As[c][r] = (gr < M) ? A[(long long)gr * K + k0 + c] : 0.f;
    }
    for (int i = threadIdx.x; i < KT * TS; i += 256) {
      int r = i >> 6, c = i & 63;
      Bs[r][c] = B[(long long)(k0 + r) * N + col0 + c];
    }
    __syncthreads();
#pragma unroll
    for (int kk = 0; kk < KT; ++kk) {
      float a[4], b[4];
#pragma unroll
      for (int i = 0; i < 4; i++) a[i] = As[kk][ty * 4 + i];
#pragma unroll
      for (int j = 0; j < 4; j++) b[j] = Bs[kk][tx * 4 + j];
#pragma unroll
      for (int i = 0; i < 4; i++)
#pragma unroll
        for (int j = 0; j < 4; j++) acc[i][j] += a[i] * b[j];
    }
    __syncthreads();
  }
#pragma unroll
  for (int i = 0; i < 4; i++) {
    int gr = row0 + ty * 4 + i;
    if (gr >= M) continue;
#pragma unroll
    for (int j = 0; j < 4; j++)
      C[(long long)gr * N + col0 + tx * 4 + j] = acc[i][j];
  }
}

// -------- per-node attention scores: a_s[n,h] = <h[n,h,:], att_s[h,:]> -----
__global__ __launch_bounds__(256) void att_score_kernel(
    const float* __restrict__ h, const float* __restrict__ att_s,
    const float* __restrict__ att_d, float* __restrict__ a_s,
    float* __restrict__ a_d) {
  const int n = blockIdx.x;
  const int head = threadIdx.x >> 6;
  const int lane = threadIdx.x & 63;
  const float v = h[n * HC + head * CDIM + lane];
  float s = v * att_s[head * CDIM + lane];
  float d = v * att_d[head * CDIM + lane];
#pragma unroll
  for (int off = 32; off > 0; off >>= 1) {
    s += __shfl_down(s, off);
    d += __shfl_down(d, off);
  }
  if (lane == 0) {
    a_s[n * HEADS + head] = s;
    a_d[n * HEADS + head] = d;
  }
}

// ======================= CSR construction (per call) =======================
__global__ __launch_bounds__(256) void deg_count_kernel(
    const int* __restrict__ dst, int* __restrict__ deg, int E_raw, int Etot) {
  const int e = blockIdx.x * 256 + threadIdx.x;
  if (e >= Etot) return;
  const int d = (e < E_raw) ? dst[e] : (e - E_raw);
  atomicAdd(&deg[d], 1);
}

__global__ __launch_bounds__(256) void scan_block_kernel(
    const int* __restrict__ deg, int* __restrict__ incl,
    int* __restrict__ bsum, int N) {
  __shared__ int sm[256];
  const int t = threadIdx.x;
  const int i = blockIdx.x * 256 + t;
  int v = (i < N) ? deg[i] : 0;
  sm[t] = v;
  __syncthreads();
#pragma unroll
  for (int off = 1; off < 256; off <<= 1) {
    int x = (t >= off) ? sm[t - off] : 0;
    __syncthreads();
    sm[t] += x;
    __syncthreads();
  }
  if (i < N) incl[i] = sm[t];
  if (t == 255) bsum[blockIdx.x] = sm[255];
}

__global__ __launch_bounds__(256) void scan_top_kernel(
    const int* __restrict__ bsum, int* __restrict__ boff, int nb) {
  __shared__ int sm[256];
  const int t = threadIdx.x;
  int v = (t < nb) ? bsum[t] : 0;
  sm[t] = v;
  __syncthreads();
#pragma unroll
  for (int off = 1; off < 256; off <<= 1) {
    int x = (t >= off) ? sm[t - off] : 0;
    __syncthreads();
    sm[t] += x;
    __syncthreads();
  }
  if (t < nb) boff[t] = sm[t] - v;  // exclusive
}

__global__ __launch_bounds__(256) void scan_final_kernel(
    const int* __restrict__ deg, const int* __restrict__ incl,
    const int* __restrict__ boff, int* __restrict__ row_ptr,
    int* __restrict__ cursor, int N, int Etot) {
  const int i = blockIdx.x * 256 + threadIdx.x;
  if (i == 0) row_ptr[N] = Etot;
  if (i >= N) return;
  const int v = boff[blockIdx.x] + incl[i] - deg[i];
  row_ptr[i] = v;
  cursor[i] = v;
}

__global__ __launch_bounds__(256) void csr_scatter_kernel(
    const int* __restrict__ src, const int* __restrict__ dst,
    int* __restrict__ cursor, int* __restrict__ csr_src, int E_raw, int Etot) {
  const int e = blockIdx.x * 256 + threadIdx.x;
  if (e >= Etot) return;
  const int s = (e < E_raw) ? src[e] : (e - E_raw);
  const int d = (e < E_raw) ? dst[e] : (e - E_raw);
  const int pos = atomicAdd(&cursor[d], 1);
  csr_src[pos] = s;
}

// ================= fused softmax + aggregation (gather) ====================
// one block per dst node. thread t: slot = t>>6 (edge subset, stride 4),
// tc = t&63 (channel quad -> channels 4tc..4tc+3, head hh = tc>>4).
// Per slot: acc4[c] += exp(leaky(a_s[s]+a_d[n])) * h[s,c], den += exp.
// LDS reduce across slots; divide; epilogue per mode.
// mode 0: out[n,c]   = ELU(v + b[c])          (layer 1, [N,256])
// mode 1: out[n,c64] = mean_h(v) + b[c64]     (layer 2, [N,64])
__global__ __launch_bounds__(256) void gat_aggregate_kernel(
    const int* __restrict__ row_ptr, const int* __restrict__ csr_src,
    const float* __restrict__ h, const float* __restrict__ a_s,
    const float* __restrict__ a_d, const float* __restrict__ b,
    float* __restrict__ out, int mode) {
  const int n = blockIdx.x;
  const int t = threadIdx.x;
  const int tc = t & 63;
  const int slot = t >> 6;
  const int hh = tc >> 4;
  const float ad = a_d[n * HEADS + hh];
  const int beg = row_ptr[n];
  const int end = row_ptr[n + 1];
  float4 acc = {0.f, 0.f, 0.f, 0.f};
  float den = 0.f;
  for (int i = beg + slot; i < end; i += 4) {
    const int s = csr_src[i];
    float a = a_s[s * HEADS + hh] + ad;
    a = (a > 0.f) ? a : 0.2f * a;  // leaky_relu slope 0.2
    const float ex = __expf(a);
    den += ex;
    const float4 hv = *(const float4*)(h + (size_t)s * HC + 4 * tc);
    acc.x += ex * hv.x;
    acc.y += ex * hv.y;
    acc.z += ex * hv.z;
    acc.w += ex * hv.w;
  }
  __shared__ float4 smacc[256];
  __shared__ float smden[256];
  smacc[t] = acc;
  smden[t] = den;
  __syncthreads();
  if (slot == 0) {
    const float4 a0 = smacc[tc];
    const float4 a1 = smacc[tc + 64];
    const float4 a2 = smacc[tc + 128];
    const float4 a3 = smacc[tc + 192];
    const float dtot = smden[hh * 16] + smden[64 + hh * 16] +
                       smden[128 + hh * 16] + smden[192 + hh * 16];
    const float inv = 1.f / dtot;
    float4 v;
    v.x = (a0.x + a1.x + a2.x + a3.x) * inv;
    v.y = (a0.y + a1.y + a2.y + a3.y) * inv;
    v.z = (a0.z + a1.z + a2.z + a3.z) * inv;
    v.w = (a0.w + a1.w + a2.w + a3.w) * inv;
    if (mode == 0) {
      const float4 bb = *(const float4*)(b + 4 * tc);
      float4 u;
      u.x = v.x + bb.x; u.x = (u.x > 0.f) ? u.x : (__expf(u.x) - 1.f);
      u.y = v.y + bb.y; u.y = (u.y > 0.f) ? u.y : (__expf(u.y) - 1.f);
      u.z = v.z + bb.z; u.z = (u.z > 0.f) ? u.z : (__expf(u.z) - 1.f);
      u.w = v.w + bb.w; u.w = (u.w > 0.f) ? u.w : (__expf(u.w) - 1.f);
      *(float4*)(out + (size_t)n * HC + 4 * tc) = u;
    } else {
      smacc[tc] = v;  // stash for head-mean
    }
  }
  if (mode == 1) {
    __syncthreads();
    if (t < 16) {
      const float4 v0 = smacc[t];
      const float4 v1 = smacc[t + 16];
      const float4 v2 = smacc[t + 32];
      const float4 v3 = smacc[t + 48];
      const float4 bb = *(const float4*)(b + 4 * t);
      float4 m;
      m.x = 0.25f * (v0.x + v1.x + v2.x + v3.x) + bb.x;
      m.y = 0.25f * (v0.y + v1.y + v2.y + v3.y) + bb.y;
      m.z = 0.25f * (v0.z + v1.z + v2.z + v3.z) + bb.z;
      m.w = 0.25f * (v0.w + v1.w + v2.w + v3.w) + bb.w;
      *(float4*)(out + (size_t)n * CDIM + 4 * t) = m;
    }
  }
}

// -------- final: d_out[n,j] = out2[n,:] @ Wout[:,j] + bout[j] --------------
__global__ __launch_bounds__(256) void final_gemm_kernel(
    const float* __restrict__ X, const float* __restrict__ W,
    const float* __restrict__ b, float* __restrict__ out, int total) {
  const int i = blockIdx.x * 256 + threadIdx.x;
  if (i >= total) return;
  const int n = i >> 4, j = i & 15;
  float s = b[j];
#pragma unroll
  for (int k = 0; k < CDIM; ++k) s += X[n * CDIM + k] * W[k * 16 + j];
  out[i] = s;
}

extern "C" void kernel_launch(void* const* d_in, const int* in_sizes, int n_in,
                              void* d_out, int out_size, void* d_ws, size_t ws_size,
                              hipStream_t stream) {
  const float* x      = (const float*)d_in[0];
  const int*   eidx   = (const int*)d_in[1];
  const float* W1     = (const float*)d_in[2];
  const float* att_s1 = (const float*)d_in[3];
  const float* att_d1 = (const float*)d_in[4];
  const float* b1     = (const float*)d_in[5];
  const float* W2     = (const float*)d_in[6];
  const float* att_s2 = (const float*)d_in[7];
  const float* att_d2 = (const float*)d_in[8];
  const float* b2     = (const float*)d_in[9];
  const float* Wout   = (const float*)d_in[10];
  const float* bout   = (const float*)d_in[11];
  float* out          = (float*)d_out;

  const int N     = in_sizes[0] / 128;   // 20000
  const int E_raw = in_sizes[1] / 2;     // 640000
  const int Etot  = E_raw + N;           // + self loops
  const int* src = eidx;
  const int* dst = eidx + E_raw;
  const int NB = (N + 255) / 256;        // 79 scan blocks

  // ---- workspace layout ----
  float* ws = (float*)d_ws;
  float* buf_h    = ws;                        // [N,256]
  float* buf_agg  = buf_h + (size_t)N * HC;    // [N,256] layer-1 ELU output
  float* buf_as   = buf_agg + (size_t)N * HC;  // [N,4]
  float* buf_ad   = buf_as + (size_t)N * HEADS;
  float* buf_out2 = buf_ad + (size_t)N * HEADS;       // [N,64]
  int* deg     = (int*)(buf_out2 + (size_t)N * CDIM); // [N]
  int* incl    = deg + N;                             // [N]
  int* row_ptr = incl + N;                            // [N+1]
  int* cursor  = row_ptr + (N + 1);                   // [N]
  int* bsum    = cursor + N;                          // [NB]
  int* boff    = bsum + NB;                           // [NB]
  int* csr_src = boff + NB;                           // [Etot]

  const dim3 blk(256);
  const dim3 g_gemm((N + TS - 1) / TS, HC / TS);
  const int g_edge = (Etot + 255) / 256;

  // ================= CSR build (shared by both layers) =================
  hipMemsetAsync(deg, 0, (size_t)N * sizeof(int), stream);
  deg_count_kernel<<<g_edge, blk, 0, stream>>>(dst, deg, E_raw, Etot);
  scan_block_kernel<<<NB, blk, 0, stream>>>(deg, incl, bsum, N);
  scan_top_kernel<<<1, blk, 0, stream>>>(bsum, boff, NB);
  scan_final_kernel<<<NB, blk, 0, stream>>>(deg, incl, boff, row_ptr, cursor, N, Etot);
  csr_scatter_kernel<<<g_edge, blk, 0, stream>>>(src, dst, cursor, csr_src, E_raw, Etot);

  // ================= Layer 1 =================
  gemm_f32<<<g_gemm, blk, 0, stream>>>(x, W1, buf_h, N, HC, 128);
  att_score_kernel<<<N, blk, 0, stream>>>(buf_h, att_s1, att_d1, buf_as, buf_ad);
  gat_aggregate_kernel<<<N, blk, 0, stream>>>(row_ptr, csr_src, buf_h, buf_as,
                                              buf_ad, b1, buf_agg, 0);

  // ================= Layer 2 =================
  gemm_f32<<<g_gemm, blk, 0, stream>>>(buf_agg, W2, buf_h, N, HC, HC);
  att_score_kernel<<<N, blk, 0, stream>>>(buf_h, att_s2, att_d2, buf_as, buf_ad);
  gat_aggregate_kernel<<<N, blk, 0, stream>>>(row_ptr, csr_src, buf_h, buf_as,
                                              buf_ad, b2, buf_out2, 1);

  // ================= Output head =================
  final_gemm_kernel<<<(N * 16 + 255) / 256, blk, 0, stream>>>(buf_out2, Wout, bout,
                                                              out, N * 16);
}

// Round 4
// 454.259 us; speedup vs baseline: 3.1047x; 1.0160x over previous
//
#include <hip/hip_runtime.h>
#include <hip/hip_bf16.h>

// ---------------------------------------------------------------------------
// 2-layer GAT (PyG GATConv semantics), all-f32 pipeline.
// Round 4: gat_aggregate edge loop manually unrolled x4 — 4 independent
// float4 h-gathers in flight per lane (MLP), batched csr_src/a_s loads.
// ---------------------------------------------------------------------------

#define HEADS 4
#define CDIM 64
#define HC 256  // HEADS*CDIM

// ---------------- f32 tiled GEMM: C[M,N] = A[M,K] @ B[K,N] -----------------
#define TS 64
#define KT 16
__global__ __launch_bounds__(256) void gemm_f32(
    const float* __restrict__ A, const float* __restrict__ B,
    float* __restrict__ C, int M, int N, int K) {
  __shared__ float As[KT][TS + 1];
  __shared__ float Bs[KT][TS + 1];
  const int tx = threadIdx.x & 15;
  const int ty = threadIdx.x >> 4;
  const int row0 = blockIdx.x * TS;
  const int col0 = blockIdx.y * TS;
  float acc[4][4] = {};
  for (int k0 = 0; k0 < K; k0 += KT) {
    for (int i = threadIdx.x; i < TS * KT; i += 256) {
      int r = i >> 4, c = i & 15;
      int gr = row0 + r;
      As[c][r] = (gr < M) ? A[(long long)gr * K + k0 + c] : 0.f;
    }
    for (int i = threadIdx.x; i < KT * TS; i += 256) {
      int r = i >> 6, c = i & 63;
      Bs[r][c] = B[(long long)(k0 + r) * N + col0 + c];
    }
    __syncthreads();
#pragma unroll
    for (int kk = 0; kk < KT; ++kk) {
      float a[4], b[4];
#pragma unroll
      for (int i = 0; i < 4; i++) a[i] = As[kk][ty * 4 + i];
#pragma unroll
      for (int j = 0; j < 4; j++) b[j] = Bs[kk][tx * 4 + j];
#pragma unroll
      for (int i = 0; i < 4; i++)
#pragma unroll
        for (int j = 0; j < 4; j++) acc[i][j] += a[i] * b[j];
    }
    __syncthreads();
  }
#pragma unroll
  for (int i = 0; i < 4; i++) {
    int gr = row0 + ty * 4 + i;
    if (gr >= M) continue;
#pragma unroll
    for (int j = 0; j < 4; j++)
      C[(long long)gr * N + col0 + tx * 4 + j] = acc[i][j];
  }
}

// -------- per-node attention scores: a_s[n,h] = <h[n,h,:], att_s[h,:]> -----
__global__ __launch_bounds__(256) void att_score_kernel(
    const float* __restrict__ h, const float* __restrict__ att_s,
    const float* __restrict__ att_d, float* __restrict__ a_s,
    float* __restrict__ a_d) {
  const int n = blockIdx.x;
  const int head = threadIdx.x >> 6;
  const int lane = threadIdx.x & 63;
  const float v = h[n * HC + head * CDIM + lane];
  float s = v * att_s[head * CDIM + lane];
  float d = v * att_d[head * CDIM + lane];
#pragma unroll
  for (int off = 32; off > 0; off >>= 1) {
    s += __shfl_down(s, off);
    d += __shfl_down(d, off);
  }
  if (lane == 0) {
    a_s[n * HEADS + head] = s;
    a_d[n * HEADS + head] = d;
  }
}

// ======================= CSR construction (per call) =======================
__global__ __launch_bounds__(256) void deg_count_kernel(
    const int* __restrict__ dst, int* __restrict__ deg, int E_raw, int Etot) {
  const int e = blockIdx.x * 256 + threadIdx.x;
  if (e >= Etot) return;
  const int d = (e < E_raw) ? dst[e] : (e - E_raw);
  atomicAdd(&deg[d], 1);
}

__global__ __launch_bounds__(256) void scan_block_kernel(
    const int* __restrict__ deg, int* __restrict__ incl,
    int* __restrict__ bsum, int N) {
  __shared__ int sm[256];
  const int t = threadIdx.x;
  const int i = blockIdx.x * 256 + t;
  int v = (i < N) ? deg[i] : 0;
  sm[t] = v;
  __syncthreads();
#pragma unroll
  for (int off = 1; off < 256; off <<= 1) {
    int x = (t >= off) ? sm[t - off] : 0;
    __syncthreads();
    sm[t] += x;
    __syncthreads();
  }
  if (i < N) incl[i] = sm[t];
  if (t == 255) bsum[blockIdx.x] = sm[255];
}

__global__ __launch_bounds__(256) void scan_top_kernel(
    const int* __restrict__ bsum, int* __restrict__ boff, int nb) {
  __shared__ int sm[256];
  const int t = threadIdx.x;
  int v = (t < nb) ? bsum[t] : 0;
  sm[t] = v;
  __syncthreads();
#pragma unroll
  for (int off = 1; off < 256; off <<= 1) {
    int x = (t >= off) ? sm[t - off] : 0;
    __syncthreads();
    sm[t] += x;
    __syncthreads();
  }
  if (t < nb) boff[t] = sm[t] - v;  // exclusive
}

__global__ __launch_bounds__(256) void scan_final_kernel(
    const int* __restrict__ deg, const int* __restrict__ incl,
    const int* __restrict__ boff, int* __restrict__ row_ptr,
    int* __restrict__ cursor, int N, int Etot) {
  const int i = blockIdx.x * 256 + threadIdx.x;
  if (i == 0) row_ptr[N] = Etot;
  if (i >= N) return;
  const int v = boff[blockIdx.x] + incl[i] - deg[i];
  row_ptr[i] = v;
  cursor[i] = v;
}

__global__ __launch_bounds__(256) void csr_scatter_kernel(
    const int* __restrict__ src, const int* __restrict__ dst,
    int* __restrict__ cursor, int* __restrict__ csr_src, int E_raw, int Etot) {
  const int e = blockIdx.x * 256 + threadIdx.x;
  if (e >= Etot) return;
  const int s = (e < E_raw) ? src[e] : (e - E_raw);
  const int d = (e < E_raw) ? dst[e] : (e - E_raw);
  const int pos = atomicAdd(&cursor[d], 1);
  csr_src[pos] = s;
}

// ================= fused softmax + aggregation (gather) ====================
// one block per dst node. thread t: slot = t>>6 (edge subset, stride 4),
// tc = t&63 (channel quad), head hh = tc>>4. Edge loop unrolled x4 so each
// lane keeps 4 independent 16B gathers in flight. LDS cross-slot reduce.
// mode 0: out[n,c]   = ELU(v + b[c])          (layer 1, [N,256])
// mode 1: out[n,c64] = mean_h(v) + b[c64]     (layer 2, [N,64])
__global__ __launch_bounds__(256) void gat_aggregate_kernel(
    const int* __restrict__ row_ptr, const int* __restrict__ csr_src,
    const float* __restrict__ h, const float* __restrict__ a_s,
    const float* __restrict__ a_d, const float* __restrict__ b,
    float* __restrict__ out, int mode) {
  const int n = blockIdx.x;
  const int t = threadIdx.x;
  const int tc = t & 63;
  const int slot = t >> 6;
  const int hh = tc >> 4;
  const float ad = a_d[n * HEADS + hh];
  const int beg = row_ptr[n];
  const int end = row_ptr[n + 1];
  float4 acc = {0.f, 0.f, 0.f, 0.f};
  float den = 0.f;
  int i = beg + slot;
  // main: 4 edges per lane per iteration (stride 4 slots x 4 unroll)
  for (; i + 12 < end; i += 16) {
    const int s0 = csr_src[i];
    const int s1 = csr_src[i + 4];
    const int s2 = csr_src[i + 8];
    const int s3 = csr_src[i + 12];
    const float as0 = a_s[s0 * HEADS + hh];
    const float as1 = a_s[s1 * HEADS + hh];
    const float as2 = a_s[s2 * HEADS + hh];
    const float as3 = a_s[s3 * HEADS + hh];
    const float4 h0 = *(const float4*)(h + (size_t)s0 * HC + 4 * tc);
    const float4 h1 = *(const float4*)(h + (size_t)s1 * HC + 4 * tc);
    const float4 h2 = *(const float4*)(h + (size_t)s2 * HC + 4 * tc);
    const float4 h3 = *(const float4*)(h + (size_t)s3 * HC + 4 * tc);
    float a0 = as0 + ad; a0 = (a0 > 0.f) ? a0 : 0.2f * a0;
    float a1 = as1 + ad; a1 = (a1 > 0.f) ? a1 : 0.2f * a1;
    float a2 = as2 + ad; a2 = (a2 > 0.f) ? a2 : 0.2f * a2;
    float a3 = as3 + ad; a3 = (a3 > 0.f) ? a3 : 0.2f * a3;
    const float e0 = __expf(a0);
    const float e1 = __expf(a1);
    const float e2 = __expf(a2);
    const float e3 = __expf(a3);
    den += (e0 + e1) + (e2 + e3);
    acc.x += e0 * h0.x + e1 * h1.x + e2 * h2.x + e3 * h3.x;
    acc.y += e0 * h0.y + e1 * h1.y + e2 * h2.y + e3 * h3.y;
    acc.z += e0 * h0.z + e1 * h1.z + e2 * h2.z + e3 * h3.z;
    acc.w += e0 * h0.w + e1 * h1.w + e2 * h2.w + e3 * h3.w;
  }
  // remainder
  for (; i < end; i += 4) {
    const int s = csr_src[i];
    float a = a_s[s * HEADS + hh] + ad;
    a = (a > 0.f) ? a : 0.2f * a;
    const float ex = __expf(a);
    den += ex;
    const float4 hv = *(const float4*)(h + (size_t)s * HC + 4 * tc);
    acc.x += ex * hv.x;
    acc.y += ex * hv.y;
    acc.z += ex * hv.z;
    acc.w += ex * hv.w;
  }
  __shared__ float4 smacc[256];
  __shared__ float smden[256];
  smacc[t] = acc;
  smden[t] = den;
  __syncthreads();
  if (slot == 0) {
    const float4 a0 = smacc[tc];
    const float4 a1 = smacc[tc + 64];
    const float4 a2 = smacc[tc + 128];
    const float4 a3 = smacc[tc + 192];
    const float dtot = smden[hh * 16] + smden[64 + hh * 16] +
                       smden[128 + hh * 16] + smden[192 + hh * 16];
    const float inv = 1.f / dtot;
    float4 v;
    v.x = (a0.x + a1.x + a2.x + a3.x) * inv;
    v.y = (a0.y + a1.y + a2.y + a3.y) * inv;
    v.z = (a0.z + a1.z + a2.z + a3.z) * inv;
    v.w = (a0.w + a1.w + a2.w + a3.w) * inv;
    if (mode == 0) {
      const float4 bb = *(const float4*)(b + 4 * tc);
      float4 u;
      u.x = v.x + bb.x; u.x = (u.x > 0.f) ? u.x : (__expf(u.x) - 1.f);
      u.y = v.y + bb.y; u.y = (u.y > 0.f) ? u.y : (__expf(u.y) - 1.f);
      u.z = v.z + bb.z; u.z = (u.z > 0.f) ? u.z : (__expf(u.z) - 1.f);
      u.w = v.w + bb.w; u.w = (u.w > 0.f) ? u.w : (__expf(u.w) - 1.f);
      *(float4*)(out + (size_t)n * HC + 4 * tc) = u;
    } else {
      smacc[tc] = v;  // stash for head-mean
    }
  }
  if (mode == 1) {
    __syncthreads();
    if (t < 16) {
      const float4 v0 = smacc[t];
      const float4 v1 = smacc[t + 16];
      const float4 v2 = smacc[t + 32];
      const float4 v3 = smacc[t + 48];
      const float4 bb = *(const float4*)(b + 4 * t);
      float4 m;
      m.x = 0.25f * (v0.x + v1.x + v2.x + v3.x) + bb.x;
      m.y = 0.25f * (v0.y + v1.y + v2.y + v3.y) + bb.y;
      m.z = 0.25f * (v0.z + v1.z + v2.z + v3.z) + bb.z;
      m.w = 0.25f * (v0.w + v1.w + v2.w + v3.w) + bb.w;
      *(float4*)(out + (size_t)n * CDIM + 4 * t) = m;
    }
  }
}

// -------- final: d_out[n,j] = out2[n,:] @ Wout[:,j] + bout[j] --------------
__global__ __launch_bounds__(256) void final_gemm_kernel(
    const float* __restrict__ X, const float* __restrict__ W,
    const float* __restrict__ b, float* __restrict__ out, int total) {
  const int i = blockIdx.x * 256 + threadIdx.x;
  if (i >= total) return;
  const int n = i >> 4, j = i & 15;
  float s = b[j];
#pragma unroll
  for (int k = 0; k < CDIM; ++k) s += X[n * CDIM + k] * W[k * 16 + j];
  out[i] = s;
}

extern "C" void kernel_launch(void* const* d_in, const int* in_sizes, int n_in,
                              void* d_out, int out_size, void* d_ws, size_t ws_size,
                              hipStream_t stream) {
  const float* x      = (const float*)d_in[0];
  const int*   eidx   = (const int*)d_in[1];
  const float* W1     = (const float*)d_in[2];
  const float* att_s1 = (const float*)d_in[3];
  const float* att_d1 = (const float*)d_in[4];
  const float* b1     = (const float*)d_in[5];
  const float* W2     = (const float*)d_in[6];
  const float* att_s2 = (const float*)d_in[7];
  const float* att_d2 = (const float*)d_in[8];
  const float* b2     = (const float*)d_in[9];
  const float* Wout   = (const float*)d_in[10];
  const float* bout   = (const float*)d_in[11];
  float* out          = (float*)d_out;

  const int N     = in_sizes[0] / 128;   // 20000
  const int E_raw = in_sizes[1] / 2;     // 640000
  const int Etot  = E_raw + N;           // + self loops
  const int* src = eidx;
  const int* dst = eidx + E_raw;
  const int NB = (N + 255) / 256;        // 79 scan blocks

  // ---- workspace layout ----
  float* ws = (float*)d_ws;
  float* buf_h    = ws;                        // [N,256]
  float* buf_agg  = buf_h + (size_t)N * HC;    // [N,256] layer-1 ELU output
  float* buf_as   = buf_agg + (size_t)N * HC;  // [N,4]
  float* buf_ad   = buf_as + (size_t)N * HEADS;
  float* buf_out2 = buf_ad + (size_t)N * HEADS;       // [N,64]
  int* deg     = (int*)(buf_out2 + (size_t)N * CDIM); // [N]
  int* incl    = deg + N;                             // [N]
  int* row_ptr = incl + N;                            // [N+1]
  int* cursor  = row_ptr + (N + 1);                   // [N]
  int* bsum    = cursor + N;                          // [NB]
  int* boff    = bsum + NB;                           // [NB]
  int* csr_src = boff + NB;                           // [Etot]

  const dim3 blk(256);
  const dim3 g_gemm((N + TS - 1) / TS, HC / TS);
  const int g_edge = (Etot + 255) / 256;

  // ================= CSR build (shared by both layers) =================
  hipMemsetAsync(deg, 0, (size_t)N * sizeof(int), stream);
  deg_count_kernel<<<g_edge, blk, 0, stream>>>(dst, deg, E_raw, Etot);
  scan_block_kernel<<<NB, blk, 0, stream>>>(deg, incl, bsum, N);
  scan_top_kernel<<<1, blk, 0, stream>>>(bsum, boff, NB);
  scan_final_kernel<<<NB, blk, 0, stream>>>(deg, incl, boff, row_ptr, cursor, N, Etot);
  csr_scatter_kernel<<<g_edge, blk, 0, stream>>>(src, dst, cursor, csr_src, E_raw, Etot);

  // ================= Layer 1 =================
  gemm_f32<<<g_gemm, blk, 0, stream>>>(x, W1, buf_h, N, HC, 128);
  att_score_kernel<<<N, blk, 0, stream>>>(buf_h, att_s1, att_d1, buf_as, buf_ad);
  gat_aggregate_kernel<<<N, blk, 0, stream>>>(row_ptr, csr_src, buf_h, buf_as,
                                              buf_ad, b1, buf_agg, 0);

  // ================= Layer 2 =================
  gemm_f32<<<g_gemm, blk, 0, stream>>>(buf_agg, W2, buf_h, N, HC, HC);
  att_score_kernel<<<N, blk, 0, stream>>>(buf_h, att_s2, att_d2, buf_as, buf_ad);
  gat_aggregate_kernel<<<N, blk, 0, stream>>>(row_ptr, csr_src, buf_h, buf_as,
                                              buf_ad, b2, buf_out2, 1);

  // ================= Output head =================
  final_gemm_kernel<<<(N * 16 + 255) / 256, blk, 0, stream>>>(buf_out2, Wout, bout,
                                                              out, N * 16);
}

// Round 5
// 415.208 us; speedup vs baseline: 3.3967x; 1.0941x over previous
//
#include <hip/hip_runtime.h>
#include <hip/hip_bf16.h>

// ---------------------------------------------------------------------------
// 2-layer GAT (PyG GATConv semantics), all-f32 pipeline.
// Round 5: gat_aggregate head-partitioned with XCD affinity — block handles
// (4 nodes x 1 head); head = blockIdx & 3 so each XCD's h working-set is a
// 5.1 MB head-slice (L2-sized) instead of the full 20.5 MB table.
// Wave: quad = edge slot (4 edges in flight), lane&15 = channel quad (f4).
// Cross-quad reduce via shfl_xor; no LDS/barriers in the hot kernel.
// ---------------------------------------------------------------------------

#define HEADS 4
#define CDIM 64
#define HC 256  // HEADS*CDIM

// ---------------- f32 tiled GEMM: C[M,N] = A[M,K] @ B[K,N] -----------------
#define TS 64
#define KT 16
__global__ __launch_bounds__(256) void gemm_f32(
    const float* __restrict__ A, const float* __restrict__ B,
    float* __restrict__ C, int M, int N, int K) {
  __shared__ float As[KT][TS + 1];
  __shared__ float Bs[KT][TS + 1];
  const int tx = threadIdx.x & 15;
  const int ty = threadIdx.x >> 4;
  const int row0 = blockIdx.x * TS;
  const int col0 = blockIdx.y * TS;
  float acc[4][4] = {};
  for (int k0 = 0; k0 < K; k0 += KT) {
    for (int i = threadIdx.x; i < TS * KT; i += 256) {
      int r = i >> 4, c = i & 15;
      int gr = row0 + r;
      As[c][r] = (gr < M) ? A[(long long)gr * K + k0 + c] : 0.f;
    }
    for (int i = threadIdx.x; i < KT * TS; i += 256) {
      int r = i >> 6, c = i & 63;
      Bs[r][c] = B[(long long)(k0 + r) * N + col0 + c];
    }
    __syncthreads();
#pragma unroll
    for (int kk = 0; kk < KT; ++kk) {
      float a[4], b[4];
#pragma unroll
      for (int i = 0; i < 4; i++) a[i] = As[kk][ty * 4 + i];
#pragma unroll
      for (int j = 0; j < 4; j++) b[j] = Bs[kk][tx * 4 + j];
#pragma unroll
      for (int i = 0; i < 4; i++)
#pragma unroll
        for (int j = 0; j < 4; j++) acc[i][j] += a[i] * b[j];
    }
    __syncthreads();
  }
#pragma unroll
  for (int i = 0; i < 4; i++) {
    int gr = row0 + ty * 4 + i;
    if (gr >= M) continue;
#pragma unroll
    for (int j = 0; j < 4; j++)
      C[(long long)gr * N + col0 + tx * 4 + j] = acc[i][j];
  }
}

// -------- per-node attention scores: a_s[n,h] = <h[n,h,:], att_s[h,:]> -----
__global__ __launch_bounds__(256) void att_score_kernel(
    const float* __restrict__ h, const float* __restrict__ att_s,
    const float* __restrict__ att_d, float* __restrict__ a_s,
    float* __restrict__ a_d) {
  const int n = blockIdx.x;
  const int head = threadIdx.x >> 6;
  const int lane = threadIdx.x & 63;
  const float v = h[n * HC + head * CDIM + lane];
  float s = v * att_s[head * CDIM + lane];
  float d = v * att_d[head * CDIM + lane];
#pragma unroll
  for (int off = 32; off > 0; off >>= 1) {
    s += __shfl_down(s, off);
    d += __shfl_down(d, off);
  }
  if (lane == 0) {
    a_s[n * HEADS + head] = s;
    a_d[n * HEADS + head] = d;
  }
}

// ======================= CSR construction (per call) =======================
__global__ __launch_bounds__(256) void deg_count_kernel(
    const int* __restrict__ dst, int* __restrict__ deg, int E_raw, int Etot) {
  const int e = blockIdx.x * 256 + threadIdx.x;
  if (e >= Etot) return;
  const int d = (e < E_raw) ? dst[e] : (e - E_raw);
  atomicAdd(&deg[d], 1);
}

__global__ __launch_bounds__(256) void scan_block_kernel(
    const int* __restrict__ deg, int* __restrict__ incl,
    int* __restrict__ bsum, int N) {
  __shared__ int sm[256];
  const int t = threadIdx.x;
  const int i = blockIdx.x * 256 + t;
  int v = (i < N) ? deg[i] : 0;
  sm[t] = v;
  __syncthreads();
#pragma unroll
  for (int off = 1; off < 256; off <<= 1) {
    int x = (t >= off) ? sm[t - off] : 0;
    __syncthreads();
    sm[t] += x;
    __syncthreads();
  }
  if (i < N) incl[i] = sm[t];
  if (t == 255) bsum[blockIdx.x] = sm[255];
}

__global__ __launch_bounds__(256) void scan_top_kernel(
    const int* __restrict__ bsum, int* __restrict__ boff, int nb) {
  __shared__ int sm[256];
  const int t = threadIdx.x;
  int v = (t < nb) ? bsum[t] : 0;
  sm[t] = v;
  __syncthreads();
#pragma unroll
  for (int off = 1; off < 256; off <<= 1) {
    int x = (t >= off) ? sm[t - off] : 0;
    __syncthreads();
    sm[t] += x;
    __syncthreads();
  }
  if (t < nb) boff[t] = sm[t] - v;  // exclusive
}

__global__ __launch_bounds__(256) void scan_final_kernel(
    const int* __restrict__ deg, const int* __restrict__ incl,
    const int* __restrict__ boff, int* __restrict__ row_ptr,
    int* __restrict__ cursor, int N, int Etot) {
  const int i = blockIdx.x * 256 + threadIdx.x;
  if (i == 0) row_ptr[N] = Etot;
  if (i >= N) return;
  const int v = boff[blockIdx.x] + incl[i] - deg[i];
  row_ptr[i] = v;
  cursor[i] = v;
}

__global__ __launch_bounds__(256) void csr_scatter_kernel(
    const int* __restrict__ src, const int* __restrict__ dst,
    int* __restrict__ cursor, int* __restrict__ csr_src, int E_raw, int Etot) {
  const int e = blockIdx.x * 256 + threadIdx.x;
  if (e >= Etot) return;
  const int s = (e < E_raw) ? src[e] : (e - E_raw);
  const int d = (e < E_raw) ? dst[e] : (e - E_raw);
  const int pos = atomicAdd(&cursor[d], 1);
  csr_src[pos] = s;
}

// ================= fused softmax + aggregation (gather) ====================
// grid = N blocks (N % 4 == 0). block b: head hd = b&3, nodes 4*(b>>2)..+3
// (wave w = node). XCD round-robin => head k only on XCDs {k, k+4}: per-XCD
// h working-set = one 5.1 MB head slice.
// lane: q = lane>>4 edge slot (stride 4, unroll 4 => 4 f4 loads in flight),
// cq = lane&15 channel quad. shfl_xor(16,32) reduces across quads.
// mode 0: out[n, hd*64+c] = ELU(v + b[hd*64+c])    (layer 1)
// mode 1: out[n, hd*64+c] = v                      (head-mean done separately)
__global__ __launch_bounds__(256) void gat_aggregate_kernel(
    const int* __restrict__ row_ptr, const int* __restrict__ csr_src,
    const float* __restrict__ h, const float* __restrict__ a_s,
    const float* __restrict__ a_d, const float* __restrict__ b,
    float* __restrict__ out, int mode) {
  const int bid = blockIdx.x;
  const int hd = bid & 3;
  const int n = (bid >> 2) * 4 + (threadIdx.x >> 6);
  const int lane = threadIdx.x & 63;
  const int q = lane >> 4;
  const int cq = lane & 15;
  const float ad = a_d[n * HEADS + hd];
  const int beg = row_ptr[n];
  const int end = row_ptr[n + 1];
  const float* __restrict__ hs = h + (size_t)hd * CDIM + 4 * cq;
  float4 acc = {0.f, 0.f, 0.f, 0.f};
  float den = 0.f;
  int i = beg + q;
  for (; i + 12 < end; i += 16) {
    const int s0 = csr_src[i];
    const int s1 = csr_src[i + 4];
    const int s2 = csr_src[i + 8];
    const int s3 = csr_src[i + 12];
    const float as0 = a_s[s0 * HEADS + hd];
    const float as1 = a_s[s1 * HEADS + hd];
    const float as2 = a_s[s2 * HEADS + hd];
    const float as3 = a_s[s3 * HEADS + hd];
    const float4 h0 = *(const float4*)(hs + (size_t)s0 * HC);
    const float4 h1 = *(const float4*)(hs + (size_t)s1 * HC);
    const float4 h2 = *(const float4*)(hs + (size_t)s2 * HC);
    const float4 h3 = *(const float4*)(hs + (size_t)s3 * HC);
    float a0 = as0 + ad; a0 = (a0 > 0.f) ? a0 : 0.2f * a0;
    float a1 = as1 + ad; a1 = (a1 > 0.f) ? a1 : 0.2f * a1;
    float a2 = as2 + ad; a2 = (a2 > 0.f) ? a2 : 0.2f * a2;
    float a3 = as3 + ad; a3 = (a3 > 0.f) ? a3 : 0.2f * a3;
    const float e0 = __expf(a0);
    const float e1 = __expf(a1);
    const float e2 = __expf(a2);
    const float e3 = __expf(a3);
    den += (e0 + e1) + (e2 + e3);
    acc.x += e0 * h0.x + e1 * h1.x + e2 * h2.x + e3 * h3.x;
    acc.y += e0 * h0.y + e1 * h1.y + e2 * h2.y + e3 * h3.y;
    acc.z += e0 * h0.z + e1 * h1.z + e2 * h2.z + e3 * h3.z;
    acc.w += e0 * h0.w + e1 * h1.w + e2 * h2.w + e3 * h3.w;
  }
  for (; i < end; i += 4) {
    const int s = csr_src[i];
    float a = a_s[s * HEADS + hd] + ad;
    a = (a > 0.f) ? a : 0.2f * a;
    const float ex = __expf(a);
    den += ex;
    const float4 hv = *(const float4*)(hs + (size_t)s * HC);
    acc.x += ex * hv.x;
    acc.y += ex * hv.y;
    acc.z += ex * hv.z;
    acc.w += ex * hv.w;
  }
  // reduce across the 4 quads (lane bits 4,5)
#pragma unroll
  for (int off = 16; off <= 32; off <<= 1) {
    acc.x += __shfl_xor(acc.x, off);
    acc.y += __shfl_xor(acc.y, off);
    acc.z += __shfl_xor(acc.z, off);
    acc.w += __shfl_xor(acc.w, off);
    den   += __shfl_xor(den, off);
  }
  if (lane < 16) {
    const float inv = 1.f / den;
    float4 v;
    v.x = acc.x * inv; v.y = acc.y * inv; v.z = acc.z * inv; v.w = acc.w * inv;
    if (mode == 0) {
      const float4 bb = *(const float4*)(b + hd * CDIM + 4 * cq);
      float4 u;
      u.x = v.x + bb.x; u.x = (u.x > 0.f) ? u.x : (__expf(u.x) - 1.f);
      u.y = v.y + bb.y; u.y = (u.y > 0.f) ? u.y : (__expf(u.y) - 1.f);
      u.z = v.z + bb.z; u.z = (u.z > 0.f) ? u.z : (__expf(u.z) - 1.f);
      u.w = v.w + bb.w; u.w = (u.w > 0.f) ? u.w : (__expf(u.w) - 1.f);
      *(float4*)(out + (size_t)n * HC + hd * CDIM + 4 * cq) = u;
    } else {
      *(float4*)(out + (size_t)n * HC + hd * CDIM + 4 * cq) = v;
    }
  }
}

// -------- layer-2 epilogue: out2[n,c] = mean_h agg[n,h,c] + b2[c] ----------
__global__ __launch_bounds__(256) void mean_bias_kernel(
    const float* __restrict__ agg, const float* __restrict__ b,
    float* __restrict__ out, int total) {
  const int i = blockIdx.x * 256 + threadIdx.x;
  if (i >= total) return;
  const int n = i >> 6, c = i & 63;
  const float v = 0.25f * (agg[(size_t)n * HC + c] + agg[(size_t)n * HC + CDIM + c] +
                           agg[(size_t)n * HC + 2 * CDIM + c] +
                           agg[(size_t)n * HC + 3 * CDIM + c]);
  out[i] = v + b[c];
}

// -------- final: d_out[n,j] = out2[n,:] @ Wout[:,j] + bout[j] --------------
__global__ __launch_bounds__(256) void final_gemm_kernel(
    const float* __restrict__ X, const float* __restrict__ W,
    const float* __restrict__ b, float* __restrict__ out, int total) {
  const int i = blockIdx.x * 256 + threadIdx.x;
  if (i >= total) return;
  const int n = i >> 4, j = i & 15;
  float s = b[j];
#pragma unroll
  for (int k = 0; k < CDIM; ++k) s += X[n * CDIM + k] * W[k * 16 + j];
  out[i] = s;
}

extern "C" void kernel_launch(void* const* d_in, const int* in_sizes, int n_in,
                              void* d_out, int out_size, void* d_ws, size_t ws_size,
                              hipStream_t stream) {
  const float* x      = (const float*)d_in[0];
  const int*   eidx   = (const int*)d_in[1];
  const float* W1     = (const float*)d_in[2];
  const float* att_s1 = (const float*)d_in[3];
  const float* att_d1 = (const float*)d_in[4];
  const float* b1     = (const float*)d_in[5];
  const float* W2     = (const float*)d_in[6];
  const float* att_s2 = (const float*)d_in[7];
  const float* att_d2 = (const float*)d_in[8];
  const float* b2     = (const float*)d_in[9];
  const float* Wout   = (const float*)d_in[10];
  const float* bout   = (const float*)d_in[11];
  float* out          = (float*)d_out;

  const int N     = in_sizes[0] / 128;   // 20000
  const int E_raw = in_sizes[1] / 2;     // 640000
  const int Etot  = E_raw + N;           // + self loops
  const int* src = eidx;
  const int* dst = eidx + E_raw;
  const int NB = (N + 255) / 256;        // 79 scan blocks

  // ---- workspace layout ----
  float* ws = (float*)d_ws;
  float* buf_h    = ws;                        // [N,256]
  float* buf_agg  = buf_h + (size_t)N * HC;    // [N,256] agg1/ELU out, agg2
  float* buf_as   = buf_agg + (size_t)N * HC;  // [N,4]
  float* buf_ad   = buf_as + (size_t)N * HEADS;
  float* buf_out2 = buf_ad + (size_t)N * HEADS;       // [N,64]
  int* deg     = (int*)(buf_out2 + (size_t)N * CDIM); // [N]
  int* incl    = deg + N;                             // [N]
  int* row_ptr = incl + N;                            // [N+1]
  int* cursor  = row_ptr + (N + 1);                   // [N]
  int* bsum    = cursor + N;                          // [NB]
  int* boff    = bsum + NB;                           // [NB]
  int* csr_src = boff + NB;                           // [Etot]

  const dim3 blk(256);
  const dim3 g_gemm((N + TS - 1) / TS, HC / TS);
  const int g_edge = (Etot + 255) / 256;

  // ================= CSR build (shared by both layers) =================
  hipMemsetAsync(deg, 0, (size_t)N * sizeof(int), stream);
  deg_count_kernel<<<g_edge, blk, 0, stream>>>(dst, deg, E_raw, Etot);
  scan_block_kernel<<<NB, blk, 0, stream>>>(deg, incl, bsum, N);
  scan_top_kernel<<<1, blk, 0, stream>>>(bsum, boff, NB);
  scan_final_kernel<<<NB, blk, 0, stream>>>(deg, incl, boff, row_ptr, cursor, N, Etot);
  csr_scatter_kernel<<<g_edge, blk, 0, stream>>>(src, dst, cursor, csr_src, E_raw, Etot);

  // ================= Layer 1 =================
  gemm_f32<<<g_gemm, blk, 0, stream>>>(x, W1, buf_h, N, HC, 128);
  att_score_kernel<<<N, blk, 0, stream>>>(buf_h, att_s1, att_d1, buf_as, buf_ad);
  gat_aggregate_kernel<<<N, blk, 0, stream>>>(row_ptr, csr_src, buf_h, buf_as,
                                              buf_ad, b1, buf_agg, 0);

  // ================= Layer 2 =================
  gemm_f32<<<g_gemm, blk, 0, stream>>>(buf_agg, W2, buf_h, N, HC, HC);
  att_score_kernel<<<N, blk, 0, stream>>>(buf_h, att_s2, att_d2, buf_as, buf_ad);
  gat_aggregate_kernel<<<N, blk, 0, stream>>>(row_ptr, csr_src, buf_h, buf_as,
                                              buf_ad, b2, buf_agg, 1);
  mean_bias_kernel<<<(N * CDIM + 255) / 256, blk, 0, stream>>>(buf_agg, b2, buf_out2,
                                                               N * CDIM);

  // ================= Output head =================
  final_gemm_kernel<<<(N * 16 + 255) / 256, blk, 0, stream>>>(buf_out2, Wout, bout,
                                                              out, N * 16);
}

// Round 6
// 348.772 us; speedup vs baseline: 4.0437x; 1.1905x over previous
//
#include <hip/hip_runtime.h>
#include <hip/hip_bf16.h>

// ---------------------------------------------------------------------------
// 2-layer GAT (PyG GATConv semantics).
// Round 6: main GEMMs moved to MFMA with split-bf16 (a = hi + lo, 3 MFMA
// products hi*hi + hi*lo + lo*hi => ~f32 precision on the matrix pipe).
// W pre-packed transposed [N][K] bf16 hi/lo; A split in-register while
// staging to LDS. B fragments read directly from global (L2-resident).
// Aggregation: head-partitioned XCD-affine gather (round 5).
// ---------------------------------------------------------------------------

#define HEADS 4
#define CDIM 64
#define HC 256  // HEADS*CDIM

typedef __attribute__((ext_vector_type(8))) short bf16x8;   // 8 bf16 = 4 VGPR
typedef __attribute__((ext_vector_type(4))) float f32x4;    // MFMA acc

__device__ __forceinline__ short f32_to_bf16_rne(float v) {
  unsigned u = __float_as_uint(v);
  unsigned r = (u + 0x7FFFu + ((u >> 16) & 1u)) >> 16;
  return (short)r;
}
__device__ __forceinline__ float bf16_bits_to_f32(short s) {
  return __uint_as_float(((unsigned)(unsigned short)s) << 16);
}

// -------- one-time weight pack: W[K][256] f32 -> Wt_hi/Wt_lo [256][K] bf16 --
__global__ __launch_bounds__(256) void pack_w_kernel(
    const float* __restrict__ W, short* __restrict__ Wt_hi,
    short* __restrict__ Wt_lo, int K, int total) {
  const int i = blockIdx.x * 256 + threadIdx.x;
  if (i >= total) return;
  const int k = i >> 8, n = i & 255;   // N fixed = 256
  const float v = W[i];
  const short hi = f32_to_bf16_rne(v);
  const short lo = f32_to_bf16_rne(v - bf16_bits_to_f32(hi));
  Wt_hi[(size_t)n * K + k] = hi;
  Wt_lo[(size_t)n * K + k] = lo;
}

// ---------------- split-bf16 MFMA GEMM: C[M,256] = A[M,K] @ W[K,256] -------
// block = 128 thr (2 waves), 64 rows x 128 cols; wave w: cols w*64..+63.
// Per wave: 4 mt x 4 nt tiles of 16x16, K-step 32, 48 MFMA/k-step.
// A: f32 global -> split hi/lo bf16 in LDS (ds_read_b128 frags).
// B: bf16x8 frags straight from global Wt (L2-resident).
// Layouts (m89/m92-verified): A[m=lane&15][k=quad*8+j]; B^T n-major same;
// C/D: col=lane&15, row=quad*4+reg.
__global__ __launch_bounds__(128) void gemm_mfma_split(
    const float* __restrict__ A, const short* __restrict__ Wt_hi,
    const short* __restrict__ Wt_lo, float* __restrict__ C, int M, int K) {
  __shared__ alignas(16) short As_hi[64 * 32];
  __shared__ alignas(16) short As_lo[64 * 32];
  const int t = threadIdx.x;
  const int wave = t >> 6;
  const int lane = t & 63;
  const int quad = lane >> 4;
  const int m16 = lane & 15;
  const int row0 = blockIdx.x * 64;
  const int col0 = blockIdx.y * 128 + wave * 64;

  f32x4 acc[4][4] = {};  // [mt][nt]

  for (int k0 = 0; k0 < K; k0 += 32) {
    if (k0) __syncthreads();
    // ---- stage A tile 64rows x 32k as hi/lo bf16 (2 units per thread) ----
#pragma unroll
    for (int uu = 0; uu < 2; ++uu) {
      const int u = t + uu * 128;       // 0..255
      const int r = u >> 2, seg = u & 3;
      const int gr = row0 + r;
      float vv[8] = {0.f, 0.f, 0.f, 0.f, 0.f, 0.f, 0.f, 0.f};
      if (gr < M) {
        const float* ap = A + (size_t)gr * K + k0 + seg * 8;
        const float4 v0 = *(const float4*)ap;
        const float4 v1 = *(const float4*)(ap + 4);
        vv[0] = v0.x; vv[1] = v0.y; vv[2] = v0.z; vv[3] = v0.w;
        vv[4] = v1.x; vv[5] = v1.y; vv[6] = v1.z; vv[7] = v1.w;
      }
      bf16x8 h8, l8;
#pragma unroll
      for (int j = 0; j < 8; ++j) {
        const short hi = f32_to_bf16_rne(vv[j]);
        h8[j] = hi;
        l8[j] = f32_to_bf16_rne(vv[j] - bf16_bits_to_f32(hi));
      }
      *(bf16x8*)(As_hi + r * 32 + seg * 8) = h8;
      *(bf16x8*)(As_lo + r * 32 + seg * 8) = l8;
    }
    // ---- B frags direct from global (start early, independent of LDS) ----
    bf16x8 b_hi[4], b_lo[4];
#pragma unroll
    for (int nt = 0; nt < 4; ++nt) {
      const size_t off = (size_t)(col0 + nt * 16 + m16) * K + k0 + quad * 8;
      b_hi[nt] = *(const bf16x8*)(Wt_hi + off);
      b_lo[nt] = *(const bf16x8*)(Wt_lo + off);
    }
    __syncthreads();
    // ---- A frags from LDS ----
    bf16x8 a_hi[4], a_lo[4];
#pragma unroll
    for (int mt = 0; mt < 4; ++mt) {
      const int off = (mt * 16 + m16) * 32 + quad * 8;
      a_hi[mt] = *(const bf16x8*)(As_hi + off);
      a_lo[mt] = *(const bf16x8*)(As_lo + off);
    }
    // ---- 48 MFMA: hi*hi + hi*lo + lo*hi ----
#pragma unroll
    for (int mt = 0; mt < 4; ++mt)
#pragma unroll
      for (int nt = 0; nt < 4; ++nt) {
        acc[mt][nt] = __builtin_amdgcn_mfma_f32_16x16x32_bf16(
            a_hi[mt], b_hi[nt], acc[mt][nt], 0, 0, 0);
        acc[mt][nt] = __builtin_amdgcn_mfma_f32_16x16x32_bf16(
            a_hi[mt], b_lo[nt], acc[mt][nt], 0, 0, 0);
        acc[mt][nt] = __builtin_amdgcn_mfma_f32_16x16x32_bf16(
            a_lo[mt], b_hi[nt], acc[mt][nt], 0, 0, 0);
      }
  }
  // ---- epilogue: C/D layout col=lane&15, row=quad*4+reg ----
#pragma unroll
  for (int mt = 0; mt < 4; ++mt)
#pragma unroll
    for (int r = 0; r < 4; ++r) {
      const int gr = row0 + mt * 16 + quad * 4 + r;
      if (gr < M) {
#pragma unroll
        for (int nt = 0; nt < 4; ++nt)
          C[(size_t)gr * HC + col0 + nt * 16 + m16] = acc[mt][nt][r];
      }
    }
}

// -------- per-node attention scores: a_s[n,h] = <h[n,h,:], att_s[h,:]> -----
__global__ __launch_bounds__(256) void att_score_kernel(
    const float* __restrict__ h, const float* __restrict__ att_s,
    const float* __restrict__ att_d, float* __restrict__ a_s,
    float* __restrict__ a_d) {
  const int n = blockIdx.x;
  const int head = threadIdx.x >> 6;
  const int lane = threadIdx.x & 63;
  const float v = h[n * HC + head * CDIM + lane];
  float s = v * att_s[head * CDIM + lane];
  float d = v * att_d[head * CDIM + lane];
#pragma unroll
  for (int off = 32; off > 0; off >>= 1) {
    s += __shfl_down(s, off);
    d += __shfl_down(d, off);
  }
  if (lane == 0) {
    a_s[n * HEADS + head] = s;
    a_d[n * HEADS + head] = d;
  }
}

// ======================= CSR construction (per call) =======================
__global__ __launch_bounds__(256) void deg_count_kernel(
    const int* __restrict__ dst, int* __restrict__ deg, int E_raw, int Etot) {
  const int e = blockIdx.x * 256 + threadIdx.x;
  if (e >= Etot) return;
  const int d = (e < E_raw) ? dst[e] : (e - E_raw);
  atomicAdd(&deg[d], 1);
}

__global__ __launch_bounds__(256) void scan_block_kernel(
    const int* __restrict__ deg, int* __restrict__ incl,
    int* __restrict__ bsum, int N) {
  __shared__ int sm[256];
  const int t = threadIdx.x;
  const int i = blockIdx.x * 256 + t;
  int v = (i < N) ? deg[i] : 0;
  sm[t] = v;
  __syncthreads();
#pragma unroll
  for (int off = 1; off < 256; off <<= 1) {
    int x = (t >= off) ? sm[t - off] : 0;
    __syncthreads();
    sm[t] += x;
    __syncthreads();
  }
  if (i < N) incl[i] = sm[t];
  if (t == 255) bsum[blockIdx.x] = sm[255];
}

__global__ __launch_bounds__(256) void scan_top_kernel(
    const int* __restrict__ bsum, int* __restrict__ boff, int nb) {
  __shared__ int sm[256];
  const int t = threadIdx.x;
  int v = (t < nb) ? bsum[t] : 0;
  sm[t] = v;
  __syncthreads();
#pragma unroll
  for (int off = 1; off < 256; off <<= 1) {
    int x = (t >= off) ? sm[t - off] : 0;
    __syncthreads();
    sm[t] += x;
    __syncthreads();
  }
  if (t < nb) boff[t] = sm[t] - v;  // exclusive
}

__global__ __launch_bounds__(256) void scan_final_kernel(
    const int* __restrict__ deg, const int* __restrict__ incl,
    const int* __restrict__ boff, int* __restrict__ row_ptr,
    int* __restrict__ cursor, int N, int Etot) {
  const int i = blockIdx.x * 256 + threadIdx.x;
  if (i == 0) row_ptr[N] = Etot;
  if (i >= N) return;
  const int v = boff[blockIdx.x] + incl[i] - deg[i];
  row_ptr[i] = v;
  cursor[i] = v;
}

__global__ __launch_bounds__(256) void csr_scatter_kernel(
    const int* __restrict__ src, const int* __restrict__ dst,
    int* __restrict__ cursor, int* __restrict__ csr_src, int E_raw, int Etot) {
  const int e = blockIdx.x * 256 + threadIdx.x;
  if (e >= Etot) return;
  const int s = (e < E_raw) ? src[e] : (e - E_raw);
  const int d = (e < E_raw) ? dst[e] : (e - E_raw);
  const int pos = atomicAdd(&cursor[d], 1);
  csr_src[pos] = s;
}

// ================= fused softmax + aggregation (gather) ====================
// grid = N blocks. block b: head hd = b&3 (XCD-affine), nodes 4*(b>>2)..+3.
// lane: q = lane>>4 edge slot (stride 4, unroll 4), cq = lane&15 chan quad.
__global__ __launch_bounds__(256) void gat_aggregate_kernel(
    const int* __restrict__ row_ptr, const int* __restrict__ csr_src,
    const float* __restrict__ h, const float* __restrict__ a_s,
    const float* __restrict__ a_d, const float* __restrict__ b,
    float* __restrict__ out, int mode) {
  const int bid = blockIdx.x;
  const int hd = bid & 3;
  const int n = (bid >> 2) * 4 + (threadIdx.x >> 6);
  const int lane = threadIdx.x & 63;
  const int q = lane >> 4;
  const int cq = lane & 15;
  const float ad = a_d[n * HEADS + hd];
  const int beg = row_ptr[n];
  const int end = row_ptr[n + 1];
  const float* __restrict__ hs = h + (size_t)hd * CDIM + 4 * cq;
  float4 acc = {0.f, 0.f, 0.f, 0.f};
  float den = 0.f;
  int i = beg + q;
  for (; i + 12 < end; i += 16) {
    const int s0 = csr_src[i];
    const int s1 = csr_src[i + 4];
    const int s2 = csr_src[i + 8];
    const int s3 = csr_src[i + 12];
    const float as0 = a_s[s0 * HEADS + hd];
    const float as1 = a_s[s1 * HEADS + hd];
    const float as2 = a_s[s2 * HEADS + hd];
    const float as3 = a_s[s3 * HEADS + hd];
    const float4 h0 = *(const float4*)(hs + (size_t)s0 * HC);
    const float4 h1 = *(const float4*)(hs + (size_t)s1 * HC);
    const float4 h2 = *(const float4*)(hs + (size_t)s2 * HC);
    const float4 h3 = *(const float4*)(hs + (size_t)s3 * HC);
    float a0 = as0 + ad; a0 = (a0 > 0.f) ? a0 : 0.2f * a0;
    float a1 = as1 + ad; a1 = (a1 > 0.f) ? a1 : 0.2f * a1;
    float a2 = as2 + ad; a2 = (a2 > 0.f) ? a2 : 0.2f * a2;
    float a3 = as3 + ad; a3 = (a3 > 0.f) ? a3 : 0.2f * a3;
    const float e0 = __expf(a0);
    const float e1 = __expf(a1);
    const float e2 = __expf(a2);
    const float e3 = __expf(a3);
    den += (e0 + e1) + (e2 + e3);
    acc.x += e0 * h0.x + e1 * h1.x + e2 * h2.x + e3 * h3.x;
    acc.y += e0 * h0.y + e1 * h1.y + e2 * h2.y + e3 * h3.y;
    acc.z += e0 * h0.z + e1 * h1.z + e2 * h2.z + e3 * h3.z;
    acc.w += e0 * h0.w + e1 * h1.w + e2 * h2.w + e3 * h3.w;
  }
  for (; i < end; i += 4) {
    const int s = csr_src[i];
    float a = a_s[s * HEADS + hd] + ad;
    a = (a > 0.f) ? a : 0.2f * a;
    const float ex = __expf(a);
    den += ex;
    const float4 hv = *(const float4*)(hs + (size_t)s * HC);
    acc.x += ex * hv.x;
    acc.y += ex * hv.y;
    acc.z += ex * hv.z;
    acc.w += ex * hv.w;
  }
#pragma unroll
  for (int off = 16; off <= 32; off <<= 1) {
    acc.x += __shfl_xor(acc.x, off);
    acc.y += __shfl_xor(acc.y, off);
    acc.z += __shfl_xor(acc.z, off);
    acc.w += __shfl_xor(acc.w, off);
    den   += __shfl_xor(den, off);
  }
  if (lane < 16) {
    const float inv = 1.f / den;
    float4 v;
    v.x = acc.x * inv; v.y = acc.y * inv; v.z = acc.z * inv; v.w = acc.w * inv;
    if (mode == 0) {
      const float4 bb = *(const float4*)(b + hd * CDIM + 4 * cq);
      float4 u;
      u.x = v.x + bb.x; u.x = (u.x > 0.f) ? u.x : (__expf(u.x) - 1.f);
      u.y = v.y + bb.y; u.y = (u.y > 0.f) ? u.y : (__expf(u.y) - 1.f);
      u.z = v.z + bb.z; u.z = (u.z > 0.f) ? u.z : (__expf(u.z) - 1.f);
      u.w = v.w + bb.w; u.w = (u.w > 0.f) ? u.w : (__expf(u.w) - 1.f);
      *(float4*)(out + (size_t)n * HC + hd * CDIM + 4 * cq) = u;
    } else {
      *(float4*)(out + (size_t)n * HC + hd * CDIM + 4 * cq) = v;
    }
  }
}

// -------- layer-2 epilogue: out2[n,c] = mean_h agg[n,h,c] + b2[c] ----------
__global__ __launch_bounds__(256) void mean_bias_kernel(
    const float* __restrict__ agg, const float* __restrict__ b,
    float* __restrict__ out, int total) {
  const int i = blockIdx.x * 256 + threadIdx.x;
  if (i >= total) return;
  const int n = i >> 6, c = i & 63;
  const float v = 0.25f * (agg[(size_t)n * HC + c] + agg[(size_t)n * HC + CDIM + c] +
                           agg[(size_t)n * HC + 2 * CDIM + c] +
                           agg[(size_t)n * HC + 3 * CDIM + c]);
  out[i] = v + b[c];
}

// -------- final: d_out[n,j] = out2[n,:] @ Wout[:,j] + bout[j] --------------
__global__ __launch_bounds__(256) void final_gemm_kernel(
    const float* __restrict__ X, const float* __restrict__ W,
    const float* __restrict__ b, float* __restrict__ out, int total) {
  const int i = blockIdx.x * 256 + threadIdx.x;
  if (i >= total) return;
  const int n = i >> 4, j = i & 15;
  float s = b[j];
#pragma unroll
  for (int k = 0; k < CDIM; ++k) s += X[n * CDIM + k] * W[k * 16 + j];
  out[i] = s;
}

extern "C" void kernel_launch(void* const* d_in, const int* in_sizes, int n_in,
                              void* d_out, int out_size, void* d_ws, size_t ws_size,
                              hipStream_t stream) {
  const float* x      = (const float*)d_in[0];
  const int*   eidx   = (const int*)d_in[1];
  const float* W1     = (const float*)d_in[2];
  const float* att_s1 = (const float*)d_in[3];
  const float* att_d1 = (const float*)d_in[4];
  const float* b1     = (const float*)d_in[5];
  const float* W2     = (const float*)d_in[6];
  const float* att_s2 = (const float*)d_in[7];
  const float* att_d2 = (const float*)d_in[8];
  const float* b2     = (const float*)d_in[9];
  const float* Wout   = (const float*)d_in[10];
  const float* bout   = (const float*)d_in[11];
  float* out          = (float*)d_out;

  const int N     = in_sizes[0] / 128;   // 20000
  const int E_raw = in_sizes[1] / 2;     // 640000
  const int Etot  = E_raw + N;           // + self loops
  const int* src = eidx;
  const int* dst = eidx + E_raw;
  const int NB = (N + 255) / 256;        // 79 scan blocks

  // ---- workspace layout ----
  float* ws = (float*)d_ws;
  float* buf_h    = ws;                        // [N,256]
  float* buf_agg  = buf_h + (size_t)N * HC;    // [N,256] agg1/ELU out, agg2
  float* buf_as   = buf_agg + (size_t)N * HC;  // [N,4]
  float* buf_ad   = buf_as + (size_t)N * HEADS;
  float* buf_out2 = buf_ad + (size_t)N * HEADS;       // [N,64]
  int* deg     = (int*)(buf_out2 + (size_t)N * CDIM); // [N]
  int* incl    = deg + N;                             // [N]
  int* row_ptr = incl + N;                            // [N+1]
  int* cursor  = row_ptr + (N + 1);                   // [N]
  int* bsum    = cursor + N;                          // [NB]
  int* boff    = bsum + NB;                           // [NB]
  int* csr_src = boff + NB;                           // [Etot]
  // packed weights (16B aligned)
  uintptr_t wp = ((uintptr_t)(csr_src + Etot) + 15) & ~(uintptr_t)15;
  short* wt1_hi = (short*)wp;                 // [256][128]
  short* wt1_lo = wt1_hi + 256 * 128;
  short* wt2_hi = wt1_lo + 256 * 128;         // [256][256]
  short* wt2_lo = wt2_hi + 256 * 256;

  const dim3 blk(256);
  const int g_edge = (Etot + 255) / 256;
  const dim3 g_gemm((N + 63) / 64, 2);
  const dim3 blk_gemm(128);

  // ================= weight pack + CSR build =================
  pack_w_kernel<<<(128 * 256 + 255) / 256, blk, 0, stream>>>(W1, wt1_hi, wt1_lo,
                                                             128, 128 * 256);
  pack_w_kernel<<<(256 * 256 + 255) / 256, blk, 0, stream>>>(W2, wt2_hi, wt2_lo,
                                                             256, 256 * 256);
  hipMemsetAsync(deg, 0, (size_t)N * sizeof(int), stream);
  deg_count_kernel<<<g_edge, blk, 0, stream>>>(dst, deg, E_raw, Etot);
  scan_block_kernel<<<NB, blk, 0, stream>>>(deg, incl, bsum, N);
  scan_top_kernel<<<1, blk, 0, stream>>>(bsum, boff, NB);
  scan_final_kernel<<<NB, blk, 0, stream>>>(deg, incl, boff, row_ptr, cursor, N, Etot);
  csr_scatter_kernel<<<g_edge, blk, 0, stream>>>(src, dst, cursor, csr_src, E_raw, Etot);

  // ================= Layer 1 =================
  gemm_mfma_split<<<g_gemm, blk_gemm, 0, stream>>>(x, wt1_hi, wt1_lo, buf_h, N, 128);
  att_score_kernel<<<N, blk, 0, stream>>>(buf_h, att_s1, att_d1, buf_as, buf_ad);
  gat_aggregate_kernel<<<N, blk, 0, stream>>>(row_ptr, csr_src, buf_h, buf_as,
                                              buf_ad, b1, buf_agg, 0);

  // ================= Layer 2 =================
  gemm_mfma_split<<<g_gemm, blk_gemm, 0, stream>>>(buf_agg, wt2_hi, wt2_lo, buf_h,
                                                   N, 256);
  att_score_kernel<<<N, blk, 0, stream>>>(buf_h, att_s2, att_d2, buf_as, buf_ad);
  gat_aggregate_kernel<<<N, blk, 0, stream>>>(row_ptr, csr_src, buf_h, buf_as,
                                              buf_ad, b2, buf_agg, 1);
  mean_bias_kernel<<<(N * CDIM + 255) / 256, blk, 0, stream>>>(buf_agg, b2, buf_out2,
                                                               N * CDIM);

  // ================= Output head =================
  final_gemm_kernel<<<(N * 16 + 255) / 256, blk, 0, stream>>>(buf_out2, Wout, bout,
                                                              out, N * 16);
}

// Round 7
// 310.134 us; speedup vs baseline: 4.5475x; 1.1246x over previous
//
#include <hip/hip_runtime.h>
#include <hip/hip_bf16.h>
#include <hip/hip_fp16.h>

// ---------------------------------------------------------------------------
// 2-layer GAT (PyG GATConv semantics).
// Round 7:
//  - h stored ONLY as f16 [N,256] (gather table), written by the MFMA GEMM
//    epilogue; f32 h never touches memory.
//  - attention scores a_s/a_d computed inside the GEMM epilogue from the
//    accumulators (wave = one full 64-col head slice) via quad shfl-reduce.
//  - aggregate: 8 lanes/edge x 8 ch (16B f16 load), 8 slots x unroll 2.
//  - mean+bias+Wout output head fused into one wave-per-node kernel.
// ---------------------------------------------------------------------------

#define HEADS 4
#define CDIM 64
#define HC 256  // HEADS*CDIM

typedef __attribute__((ext_vector_type(8))) short bf16x8;   // 8 bf16 = 4 VGPR
typedef __attribute__((ext_vector_type(4))) float f32x4;    // MFMA acc

__device__ __forceinline__ short f32_to_bf16_rne(float v) {
  unsigned u = __float_as_uint(v);
  unsigned r = (u + 0x7FFFu + ((u >> 16) & 1u)) >> 16;
  return (short)r;
}
__device__ __forceinline__ float bf16_bits_to_f32(short s) {
  return __uint_as_float(((unsigned)(unsigned short)s) << 16);
}

// -------- one-time weight pack: W[K][256] f32 -> Wt_hi/Wt_lo [256][K] bf16 --
__global__ __launch_bounds__(256) void pack_w_kernel(
    const float* __restrict__ W, short* __restrict__ Wt_hi,
    short* __restrict__ Wt_lo, int K, int total) {
  const int i = blockIdx.x * 256 + threadIdx.x;
  if (i >= total) return;
  const int k = i >> 8, n = i & 255;   // N fixed = 256
  const float v = W[i];
  const short hi = f32_to_bf16_rne(v);
  const short lo = f32_to_bf16_rne(v - bf16_bits_to_f32(hi));
  Wt_hi[(size_t)n * K + k] = hi;
  Wt_lo[(size_t)n * K + k] = lo;
}

// ---------------- split-bf16 MFMA GEMM: h = A[M,K] @ W[K,256] --------------
// block = 128 thr (2 waves); wave w: cols col0 = by*128 + w*64 (one head).
// Epilogue: h16[M,256] f16 write + fused a_s/a_d (quad shfl reduction).
__global__ __launch_bounds__(128) void gemm_mfma_split(
    const float* __restrict__ A, const short* __restrict__ Wt_hi,
    const short* __restrict__ Wt_lo, __half* __restrict__ h16,
    const float* __restrict__ att_s, const float* __restrict__ att_d,
    float* __restrict__ a_s, float* __restrict__ a_d, int M, int K) {
  __shared__ alignas(16) short As_hi[64 * 32];
  __shared__ alignas(16) short As_lo[64 * 32];
  const int t = threadIdx.x;
  const int wave = t >> 6;
  const int lane = t & 63;
  const int quad = lane >> 4;
  const int m16 = lane & 15;
  const int row0 = blockIdx.x * 64;
  const int col0 = blockIdx.y * 128 + wave * 64;   // == head*64
  const int head = col0 >> 6;

  f32x4 acc[4][4] = {};  // [mt][nt]

  for (int k0 = 0; k0 < K; k0 += 32) {
    if (k0) __syncthreads();
    // ---- stage A tile 64rows x 32k as hi/lo bf16 (2 units per thread) ----
#pragma unroll
    for (int uu = 0; uu < 2; ++uu) {
      const int u = t + uu * 128;       // 0..255
      const int r = u >> 2, seg = u & 3;
      const int gr = row0 + r;
      float vv[8] = {0.f, 0.f, 0.f, 0.f, 0.f, 0.f, 0.f, 0.f};
      if (gr < M) {
        const float* ap = A + (size_t)gr * K + k0 + seg * 8;
        const float4 v0 = *(const float4*)ap;
        const float4 v1 = *(const float4*)(ap + 4);
        vv[0] = v0.x; vv[1] = v0.y; vv[2] = v0.z; vv[3] = v0.w;
        vv[4] = v1.x; vv[5] = v1.y; vv[6] = v1.z; vv[7] = v1.w;
      }
      bf16x8 h8, l8;
#pragma unroll
      for (int j = 0; j < 8; ++j) {
        const short hi = f32_to_bf16_rne(vv[j]);
        h8[j] = hi;
        l8[j] = f32_to_bf16_rne(vv[j] - bf16_bits_to_f32(hi));
      }
      *(bf16x8*)(As_hi + r * 32 + seg * 8) = h8;
      *(bf16x8*)(As_lo + r * 32 + seg * 8) = l8;
    }
    // ---- B frags direct from global (L2-resident) ----
    bf16x8 b_hi[4], b_lo[4];
#pragma unroll
    for (int nt = 0; nt < 4; ++nt) {
      const size_t off = (size_t)(col0 + nt * 16 + m16) * K + k0 + quad * 8;
      b_hi[nt] = *(const bf16x8*)(Wt_hi + off);
      b_lo[nt] = *(const bf16x8*)(Wt_lo + off);
    }
    __syncthreads();
    bf16x8 a_hi[4], a_lo[4];
#pragma unroll
    for (int mt = 0; mt < 4; ++mt) {
      const int off = (mt * 16 + m16) * 32 + quad * 8;
      a_hi[mt] = *(const bf16x8*)(As_hi + off);
      a_lo[mt] = *(const bf16x8*)(As_lo + off);
    }
#pragma unroll
    for (int mt = 0; mt < 4; ++mt)
#pragma unroll
      for (int nt = 0; nt < 4; ++nt) {
        acc[mt][nt] = __builtin_amdgcn_mfma_f32_16x16x32_bf16(
            a_hi[mt], b_hi[nt], acc[mt][nt], 0, 0, 0);
        acc[mt][nt] = __builtin_amdgcn_mfma_f32_16x16x32_bf16(
            a_hi[mt], b_lo[nt], acc[mt][nt], 0, 0, 0);
        acc[mt][nt] = __builtin_amdgcn_mfma_f32_16x16x32_bf16(
            a_lo[mt], b_hi[nt], acc[mt][nt], 0, 0, 0);
      }
  }
  // ---- epilogue: f16 h write + fused attention scores ----
  // C/D layout: col = col0 + nt*16 + m16, row = row0 + mt*16 + quad*4 + r
  float sa[4], da[4];
#pragma unroll
  for (int nt = 0; nt < 4; ++nt) {
    sa[nt] = att_s[col0 + nt * 16 + m16];
    da[nt] = att_d[col0 + nt * 16 + m16];
  }
#pragma unroll
  for (int mt = 0; mt < 4; ++mt)
#pragma unroll
    for (int r = 0; r < 4; ++r) {
      const int gr = row0 + mt * 16 + quad * 4 + r;
      float ps = acc[mt][0][r] * sa[0] + acc[mt][1][r] * sa[1] +
                 acc[mt][2][r] * sa[2] + acc[mt][3][r] * sa[3];
      float pd = acc[mt][0][r] * da[0] + acc[mt][1][r] * da[1] +
                 acc[mt][2][r] * da[2] + acc[mt][3][r] * da[3];
#pragma unroll
      for (int off = 1; off <= 8; off <<= 1) {
        ps += __shfl_xor(ps, off);
        pd += __shfl_xor(pd, off);
      }
      if (gr < M) {
        if (m16 == 0) {
          a_s[gr * HEADS + head] = ps;
          a_d[gr * HEADS + head] = pd;
        }
#pragma unroll
        for (int nt = 0; nt < 4; ++nt)
          h16[(size_t)gr * HC + col0 + nt * 16 + m16] =
              __float2half(acc[mt][nt][r]);
      }
    }
}

// ======================= CSR construction (per call) =======================
__global__ __launch_bounds__(256) void deg_count_kernel(
    const int* __restrict__ dst, int* __restrict__ deg, int E_raw, int Etot) {
  const int e = blockIdx.x * 256 + threadIdx.x;
  if (e >= Etot) return;
  const int d = (e < E_raw) ? dst[e] : (e - E_raw);
  atomicAdd(&deg[d], 1);
}

__global__ __launch_bounds__(256) void scan_block_kernel(
    const int* __restrict__ deg, int* __restrict__ incl,
    int* __restrict__ bsum, int N) {
  __shared__ int sm[256];
  const int t = threadIdx.x;
  const int i = blockIdx.x * 256 + t;
  int v = (i < N) ? deg[i] : 0;
  sm[t] = v;
  __syncthreads();
#pragma unroll
  for (int off = 1; off < 256; off <<= 1) {
    int x = (t >= off) ? sm[t - off] : 0;
    __syncthreads();
    sm[t] += x;
    __syncthreads();
  }
  if (i < N) incl[i] = sm[t];
  if (t == 255) bsum[blockIdx.x] = sm[255];
}

__global__ __launch_bounds__(256) void scan_top_kernel(
    const int* __restrict__ bsum, int* __restrict__ boff, int nb) {
  __shared__ int sm[256];
  const int t = threadIdx.x;
  int v = (t < nb) ? bsum[t] : 0;
  sm[t] = v;
  __syncthreads();
#pragma unroll
  for (int off = 1; off < 256; off <<= 1) {
    int x = (t >= off) ? sm[t - off] : 0;
    __syncthreads();
    sm[t] += x;
    __syncthreads();
  }
  if (t < nb) boff[t] = sm[t] - v;  // exclusive
}

__global__ __launch_bounds__(256) void scan_final_kernel(
    const int* __restrict__ deg, const int* __restrict__ incl,
    const int* __restrict__ boff, int* __restrict__ row_ptr,
    int* __restrict__ cursor, int N, int Etot) {
  const int i = blockIdx.x * 256 + threadIdx.x;
  if (i == 0) row_ptr[N] = Etot;
  if (i >= N) return;
  const int v = boff[blockIdx.x] + incl[i] - deg[i];
  row_ptr[i] = v;
  cursor[i] = v;
}

__global__ __launch_bounds__(256) void csr_scatter_kernel(
    const int* __restrict__ src, const int* __restrict__ dst,
    int* __restrict__ cursor, int* __restrict__ csr_src, int E_raw, int Etot) {
  const int e = blockIdx.x * 256 + threadIdx.x;
  if (e >= Etot) return;
  const int s = (e < E_raw) ? src[e] : (e - E_raw);
  const int d = (e < E_raw) ? dst[e] : (e - E_raw);
  const int pos = atomicAdd(&cursor[d], 1);
  csr_src[pos] = s;
}

// ================= fused softmax + aggregation (f16 gather) ================
// grid = N blocks. block b: head hd = b&3 (XCD-affine), nodes 4*(b>>2)..+3
// (wave = node). lane: q = lane>>3 edge slot (stride 8, unroll 2),
// oc = lane&7 channel octet (8 f16 ch = one 16B load).
__device__ __forceinline__ void acc_edge_f16(float ex, const uint4& u,
                                             float4& A, float4& B) {
  const __half2* hp = (const __half2*)&u;
  float2 f;
  f = __half22float2(hp[0]); A.x += ex * f.x; A.y += ex * f.y;
  f = __half22float2(hp[1]); A.z += ex * f.x; A.w += ex * f.y;
  f = __half22float2(hp[2]); B.x += ex * f.x; B.y += ex * f.y;
  f = __half22float2(hp[3]); B.z += ex * f.x; B.w += ex * f.y;
}

__global__ __launch_bounds__(256) void gat_aggregate_kernel(
    const int* __restrict__ row_ptr, const int* __restrict__ csr_src,
    const __half* __restrict__ h16, const float* __restrict__ a_s,
    const float* __restrict__ a_d, const float* __restrict__ b,
    float* __restrict__ out, int mode) {
  const int bid = blockIdx.x;
  const int hd = bid & 3;
  const int n = (bid >> 2) * 4 + (threadIdx.x >> 6);
  const int lane = threadIdx.x & 63;
  const int q = lane >> 3;
  const int oc = lane & 7;
  const float ad = a_d[n * HEADS + hd];
  const int beg = row_ptr[n];
  const int end = row_ptr[n + 1];
  const char* hbase = (const char*)h16 + hd * 128 + oc * 16;  // bytes
  const float* asb = a_s + hd;
  float4 accA = {0.f, 0.f, 0.f, 0.f}, accB = {0.f, 0.f, 0.f, 0.f};
  float den = 0.f;
  int i = beg + q;
  for (; i + 8 < end; i += 16) {
    const int s0 = csr_src[i];
    const int s1 = csr_src[i + 8];
    const float as0 = asb[s0 * 4];
    const float as1 = asb[s1 * 4];
    const uint4 u0 = *(const uint4*)(hbase + ((unsigned)s0 << 9));
    const uint4 u1 = *(const uint4*)(hbase + ((unsigned)s1 << 9));
    float a0 = as0 + ad; a0 = (a0 > 0.f) ? a0 : 0.2f * a0;
    float a1 = as1 + ad; a1 = (a1 > 0.f) ? a1 : 0.2f * a1;
    const float e0 = __expf(a0);
    const float e1 = __expf(a1);
    den += e0 + e1;
    acc_edge_f16(e0, u0, accA, accB);
    acc_edge_f16(e1, u1, accA, accB);
  }
  for (; i < end; i += 8) {
    const int s = csr_src[i];
    float a = asb[s * 4] + ad;
    a = (a > 0.f) ? a : 0.2f * a;
    const float ex = __expf(a);
    den += ex;
    const uint4 u = *(const uint4*)(hbase + ((unsigned)s << 9));
    acc_edge_f16(ex, u, accA, accB);
  }
  // reduce across the 8 slots (lane bits 3,4,5)
#pragma unroll
  for (int off = 8; off <= 32; off <<= 1) {
    accA.x += __shfl_xor(accA.x, off);
    accA.y += __shfl_xor(accA.y, off);
    accA.z += __shfl_xor(accA.z, off);
    accA.w += __shfl_xor(accA.w, off);
    accB.x += __shfl_xor(accB.x, off);
    accB.y += __shfl_xor(accB.y, off);
    accB.z += __shfl_xor(accB.z, off);
    accB.w += __shfl_xor(accB.w, off);
    den    += __shfl_xor(den, off);
  }
  if (lane < 8) {
    const float inv = 1.f / den;
    float u[8] = {accA.x * inv, accA.y * inv, accA.z * inv, accA.w * inv,
                  accB.x * inv, accB.y * inv, accB.z * inv, accB.w * inv};
    if (mode == 0) {
      const int cb = hd * CDIM + oc * 8;
#pragma unroll
      for (int k = 0; k < 8; ++k) {
        const float t = u[k] + b[cb + k];
        u[k] = (t > 0.f) ? t : (__expf(t) - 1.f);
      }
    }
    float* op = out + (size_t)n * HC + hd * CDIM + oc * 8;
    *(float4*)op = make_float4(u[0], u[1], u[2], u[3]);
    *(float4*)(op + 4) = make_float4(u[4], u[5], u[6], u[7]);
  }
}

// ---- fused output head: out[n,:] = (mean_h agg[n,h,:] + b2) @ Wout + bout --
// one wave per node; lane = channel c; 16-wide dot reduced via shfl butterfly.
__global__ __launch_bounds__(256) void final_fused_kernel(
    const float* __restrict__ agg, const float* __restrict__ b2,
    const float* __restrict__ Wout, const float* __restrict__ bout,
    float* __restrict__ out, int N) {
  const int n = blockIdx.x * 4 + (threadIdx.x >> 6);
  const int c = threadIdx.x & 63;
  if (n >= N) return;
  const float* ar = agg + (size_t)n * HC;
  const float m = 0.25f * (ar[c] + ar[c + 64] + ar[c + 128] + ar[c + 192]) +
                  b2[c];
  const float4* wr = (const float4*)(Wout + c * 16);
  const float4 w0 = wr[0], w1 = wr[1], w2 = wr[2], w3 = wr[3];
  float p[16] = {m * w0.x, m * w0.y, m * w0.z, m * w0.w,
                 m * w1.x, m * w1.y, m * w1.z, m * w1.w,
                 m * w2.x, m * w2.y, m * w2.z, m * w2.w,
                 m * w3.x, m * w3.y, m * w3.z, m * w3.w};
#pragma unroll
  for (int off = 1; off < 64; off <<= 1)
#pragma unroll
    for (int j = 0; j < 16; ++j) p[j] += __shfl_xor(p[j], off);
  if (c == 0) {
    float* op = out + (size_t)n * 16;
    *(float4*)op = make_float4(p[0] + bout[0], p[1] + bout[1],
                               p[2] + bout[2], p[3] + bout[3]);
    *(float4*)(op + 4) = make_float4(p[4] + bout[4], p[5] + bout[5],
                                     p[6] + bout[6], p[7] + bout[7]);
    *(float4*)(op + 8) = make_float4(p[8] + bout[8], p[9] + bout[9],
                                     p[10] + bout[10], p[11] + bout[11]);
    *(float4*)(op + 12) = make_float4(p[12] + bout[12], p[13] + bout[13],
                                      p[14] + bout[14], p[15] + bout[15]);
  }
}

extern "C" void kernel_launch(void* const* d_in, const int* in_sizes, int n_in,
                              void* d_out, int out_size, void* d_ws, size_t ws_size,
                              hipStream_t stream) {
  const float* x      = (const float*)d_in[0];
  const int*   eidx   = (const int*)d_in[1];
  const float* W1     = (const float*)d_in[2];
  const float* att_s1 = (const float*)d_in[3];
  const float* att_d1 = (const float*)d_in[4];
  const float* b1     = (const float*)d_in[5];
  const float* W2     = (const float*)d_in[6];
  const float* att_s2 = (const float*)d_in[7];
  const float* att_d2 = (const float*)d_in[8];
  const float* b2     = (const float*)d_in[9];
  const float* Wout   = (const float*)d_in[10];
  const float* bout   = (const float*)d_in[11];
  float* out          = (float*)d_out;

  const int N     = in_sizes[0] / 128;   // 20000
  const int E_raw = in_sizes[1] / 2;     // 640000
  const int Etot  = E_raw + N;           // + self loops
  const int* src = eidx;
  const int* dst = eidx + E_raw;
  const int NB = (N + 255) / 256;        // 79 scan blocks

  // ---- workspace layout ----
  float* ws = (float*)d_ws;
  float* buf_agg = ws;                          // [N,256] agg1/ELU out, agg2
  float* buf_as  = buf_agg + (size_t)N * HC;    // [N,4]
  float* buf_ad  = buf_as + (size_t)N * HEADS;  // [N,4]
  __half* h16    = (__half*)(buf_ad + (size_t)N * HEADS);  // [N,256] f16
  int* deg     = (int*)(h16 + (size_t)N * HC);  // [N]
  int* incl    = deg + N;
  int* row_ptr = incl + N;                      // [N+1]
  int* cursor  = row_ptr + (N + 1);
  int* bsum    = cursor + N;                    // [NB]
  int* boff    = bsum + NB;                     // [NB]
  int* csr_src = boff + NB;                     // [Etot]
  uintptr_t wp = ((uintptr_t)(csr_src + Etot) + 15) & ~(uintptr_t)15;
  short* wt1_hi = (short*)wp;                   // [256][128]
  short* wt1_lo = wt1_hi + 256 * 128;
  short* wt2_hi = wt1_lo + 256 * 128;           // [256][256]
  short* wt2_lo = wt2_hi + 256 * 256;

  const dim3 blk(256);
  const int g_edge = (Etot + 255) / 256;
  const dim3 g_gemm((N + 63) / 64, 2);
  const dim3 blk_gemm(128);

  // ================= weight pack + CSR build =================
  pack_w_kernel<<<(128 * 256 + 255) / 256, blk, 0, stream>>>(W1, wt1_hi, wt1_lo,
                                                             128, 128 * 256);
  pack_w_kernel<<<(256 * 256 + 255) / 256, blk, 0, stream>>>(W2, wt2_hi, wt2_lo,
                                                             256, 256 * 256);
  hipMemsetAsync(deg, 0, (size_t)N * sizeof(int), stream);
  deg_count_kernel<<<g_edge, blk, 0, stream>>>(dst, deg, E_raw, Etot);
  scan_block_kernel<<<NB, blk, 0, stream>>>(deg, incl, bsum, N);
  scan_top_kernel<<<1, blk, 0, stream>>>(bsum, boff, NB);
  scan_final_kernel<<<NB, blk, 0, stream>>>(deg, incl, boff, row_ptr, cursor, N, Etot);
  csr_scatter_kernel<<<g_edge, blk, 0, stream>>>(src, dst, cursor, csr_src, E_raw, Etot);

  // ================= Layer 1 =================
  gemm_mfma_split<<<g_gemm, blk_gemm, 0, stream>>>(
      x, wt1_hi, wt1_lo, h16, att_s1, att_d1, buf_as, buf_ad, N, 128);
  gat_aggregate_kernel<<<N, blk, 0, stream>>>(row_ptr, csr_src, h16, buf_as,
                                              buf_ad, b1, buf_agg, 0);

  // ================= Layer 2 =================
  gemm_mfma_split<<<g_gemm, blk_gemm, 0, stream>>>(
      buf_agg, wt2_hi, wt2_lo, h16, att_s2, att_d2, buf_as, buf_ad, N, 256);
  gat_aggregate_kernel<<<N, blk, 0, stream>>>(row_ptr, csr_src, h16, buf_as,
                                              buf_ad, b2, buf_agg, 1);

  // ================= Output head (mean + bias + Wout fused) =================
  final_fused_kernel<<<(N + 3) / 4, blk, 0, stream>>>(buf_agg, b2, Wout, bout,
                                                      out, N);
}